// Round 14
// baseline (790.033 us; speedup 1.0000x reference)
//
#include <hip/hip_runtime.h>
#include <math.h>

// -------------------------------------------------------------------------
// VQ-VAE forward, fp32, round 34: conv3_mfma 2 output rows per block.
//  - R13 was neutral: TP=3+co-tiling traded barriers for duplicated act
//    work; LDS-BW analysis shows weight-fragment reads (~0.75 KB LDS per
//    MFMA) are the floor (~38 us for convf). Fix: 2 rows/block -> each
//    weight read feeds 2 B-frags (6*nM MFMAs/tap), LDS/MFMA 1.8x lower,
//    act conversion 1.5x lower per output, 48 MFMAs/barrier (nM=8).
//    LDS: act 42.2 KB (4 rows) + wdbuf 2*nM KB = 74.2 KB (COT=128,
//    2 blocks/CU); grid.x = 32. Pack unchanged (R29 slab layout, TP=1).
//  - Everything else identical to R13 (760 us, absmax 9.77e-4).
// Remaining fp32 VALU: conv0, 1x1s, up1.
// -------------------------------------------------------------------------

#define DEV __device__ __forceinline__

DEV int rfl(int v) { return __builtin_amdgcn_readfirstlane(v); }

DEV void async_copy16(const float* g, float* l) {
  __builtin_amdgcn_global_load_lds(
      (const __attribute__((address_space(1))) void*)g,
      (__attribute__((address_space(3))) void*)l, 16, 0, 0);
}

typedef __attribute__((ext_vector_type(8))) _Float16 h16x8;
typedef __attribute__((ext_vector_type(4))) float f32x4;

DEV ushort f2h(float f) {
  _Float16 h = (_Float16)f;
  return __builtin_bit_cast(ushort, h);
}
DEV float h2f(ushort u) { return (float)__builtin_bit_cast(_Float16, u); }
DEV uint pk(ushort a, ushort b) { return (uint)a | ((uint)b << 16); }

// ---------------- weight prepack for conv3_mfma (LDS-staged) --------------
// nCh*9 slabs of nM*1024 ush, slab sid = ch*9 + kh*3 + kw (execution order).
// Within slab: m, lane l: ah 8 ush at m*1024 + (16l ^ s(l)), al at ^8,
// s(l) = (l&4) ? 8 : 0 (bank-balanced; linear DMA preserves it).
template<int CIN, int COT>
__global__ __launch_bounds__(256) void prep_w3s(
    const float* __restrict__ w, ushort* __restrict__ wpk) {
  constexpr int nCh = CIN / 32, nM = COT / 16;
  const int t = blockIdx.x * 256 + threadIdx.x;
  if (t >= 9 * nCh * nM * 64) return;
  const int l = t & 63;
  const int m = (t >> 6) % nM;
  const int sid = t / (64 * nM);
  const int ch = sid / 9, khkw = sid % 9;
  const int co = m * 16 + (l & 15);
  const int k8 = (l >> 4) * 8;
  const int sw = (16 * l) ^ ((l & 4) ? 8 : 0);
  ushort* slab = wpk + (size_t)sid * (nM * 1024) + m * 1024;
#pragma unroll
  for (int i = 0; i < 8; i++) {
    const int ci = ch * 32 + k8 + i;
    const float v = w[((size_t)co * CIN + ci) * 9 + khkw];
    const ushort hi = f2h(v);
    slab[sw + i]       = hi;
    slab[(sw ^ 8) + i] = f2h((v - h2f(hi)) * 2048.0f);
  }
}

// ---------------- weight prepack for conv4s2_mfma (LDS-staged) ------------
// 32 slabs of 8192 ush (16 KB), sid = step*8 + rr*4 + kw (execution order).
template<int CIN, int COT>
__global__ __launch_bounds__(256) void prep_w4s(
    const float* __restrict__ w, ushort* __restrict__ wpk) {
  const int t = blockIdx.x * 256 + threadIdx.x;   // 32*8*64 = 16384
  if (t >= 16384) return;
  const int l = t & 63;
  const int m = (t >> 6) & 7;
  const int sid = t >> 9;
  const int step = sid >> 3, rr = (sid >> 2) & 1, kw = sid & 3;
  const int ch = step >> 1, h = step & 1;
  const int kh = 2 * h + rr;
  const int tap = kh * 4 + kw;
  const int co = m * 16 + (l & 15);
  const int k8 = (l >> 4) * 8;
  const int sw = (16 * l) ^ ((l & 4) ? 8 : 0);
  ushort* slab = wpk + (size_t)sid * 8192 + m * 1024;
#pragma unroll
  for (int i = 0; i < 8; i++) {
    const int ci = ch * 32 + k8 + i;
    const float v = w[((size_t)co * CIN + ci) * 16 + tap];
    const ushort hi = f2h(v);
    slab[sw + i]       = hi;
    slab[(sw ^ 8) + i] = f2h((v - h2f(hi)) * 2048.0f);
  }
}

// ---------------- weight prepack for convt_mfma (LDS-staged) --------------
// nCh*16 slabs of nM*1024 ush, sid = ch*16 + idx where idx follows the
// kernel's tap execution order: ord[idx] = tap (kh*4+kw).
template<int CIN, int COT>
__global__ __launch_bounds__(256) void prep_wts(
    const float* __restrict__ w, ushort* __restrict__ wpk) {
  constexpr int nCh = CIN / 32, nM = COT / 16;
  const int t = blockIdx.x * 256 + threadIdx.x;
  if (t >= 16 * nCh * nM * 64) return;
  const int l = t & 63;
  const int m = (t >> 6) % nM;
  const int sid = t / (64 * nM);
  const int ch = sid >> 4, idx = sid & 15;
  const int ord[16] = {15, 13, 14, 12, 7, 11, 5, 6, 9, 10, 4, 8, 3, 1, 2, 0};
  const int tap = ord[idx];
  const int kh = tap >> 2, kw = tap & 3;
  const int co = m * 16 + (l & 15);
  const int k8 = (l >> 4) * 8;
  const int sw = (16 * l) ^ ((l & 4) ? 8 : 0);
  ushort* slab = wpk + (size_t)sid * (nM * 1024) + m * 1024;
#pragma unroll
  for (int i = 0; i < 8; i++) {
    const int ci = ch * 32 + k8 + i;
    const float v = w[(((size_t)ci * COT + co) * 4 + kh) * 4 + kw];
    const ushort hi = f2h(v);
    slab[sw + i]       = hi;
    slab[(sw ^ 8) + i] = f2h((v - h2f(hi)) * 2048.0f);
  }
}

// ---------------- codebook prepack for vq_mfma ----------------------------
__global__ __launch_bounds__(256) void prep_cb(
    const float* __restrict__ cb, ushort* __restrict__ cbpk) {
  const int t = blockIdx.x * 256 + threadIdx.x;   // 4096
  const int l = t & 63;
  const int m = (t >> 6) & 31;
  const int c = t >> 11;
  const int entry = m * 16 + (l & 15);
  ushort* o = cbpk + (size_t)t * 16;
#pragma unroll
  for (int i = 0; i < 8; i++) {
    const int d = c * 32 + (l >> 4) * 8 + i;
    const float v = cb[d * 512 + entry];
    const ushort hi = f2h(v);
    o[i]     = hi;
    o[8 + i] = f2h((v - h2f(hi)) * 2048.0f);
  }
}

// ---------------- codebook norms (fp64 accum -> fp32), once ---------------
__global__ __launch_bounds__(256) void cvt_cbn(
    const float* __restrict__ cb, float* __restrict__ cbn) {
  const int k = blockIdx.x * 256 + threadIdx.x;   // 0..511
  if (k >= 512) return;
  double s = 0.0;
  for (int d = 0; d < 64; d++) {
    const double c = (double)cb[d * 512 + k];
    s = fma(c, c, s);
  }
  cbn[k] = (float)s;
}

// ---------------- VQ via MFMA fp16x2: argmin + in-place quantize ----------
__global__ __launch_bounds__(256) void vq_mfma(
    const float* __restrict__ cb, const ushort* __restrict__ cbpk,
    const float* __restrict__ cbn, float* __restrict__ zq) {
  const int tid = threadIdx.x;
  const int l = tid & 63;
  const int w = rfl(tid >> 6);
  const int n = blockIdx.x >> 6, row = blockIdx.x & 63;
  float* zp = zq + (size_t)n * 262144 + row * 64;   // [d][64rows][64cols]
  const int pos = w * 16 + (l & 15);

  h16x8 zh[2], zl[2];
#pragma unroll
  for (int c = 0; c < 2; c++) {
#pragma unroll
    for (int i = 0; i < 8; i++) {
      const int d = c * 32 + (l >> 4) * 8 + i;
      const float v = zp[(size_t)d * 4096 + pos];
      const _Float16 h = (_Float16)v;
      zh[c][i] = h;
      zl[c][i] = (_Float16)((v - (float)h) * 2048.0f);
    }
  }

  const float SCL = 1.0f / 2048.0f;
  float bestd = 1e30f;
  int best = 0;
  for (int grp = 0; grp < 4; grp++) {
    f32x4 aH[8], aM[8];
#pragma unroll
    for (int m = 0; m < 8; m++) {
      aH[m] = (f32x4){0.f, 0.f, 0.f, 0.f};
      aM[m] = (f32x4){0.f, 0.f, 0.f, 0.f};
    }
#pragma unroll
    for (int c = 0; c < 2; c++) {
#pragma unroll
      for (int m = 0; m < 8; m++) {
        const ushort* ap = cbpk + ((size_t)(c * 32 + grp * 8 + m) * 64 + l) * 16;
        const h16x8 ah = *(const h16x8*)ap;
        const h16x8 al = *(const h16x8*)(ap + 8);
        aH[m] = __builtin_amdgcn_mfma_f32_16x16x32_f16(ah, zh[c], aH[m], 0, 0, 0);
        aM[m] = __builtin_amdgcn_mfma_f32_16x16x32_f16(al, zh[c], aM[m], 0, 0, 0);
        aM[m] = __builtin_amdgcn_mfma_f32_16x16x32_f16(ah, zl[c], aM[m], 0, 0, 0);
      }
    }
#pragma unroll
    for (int m = 0; m < 8; m++) {
#pragma unroll
      for (int j = 0; j < 4; j++) {
        const int k = grp * 128 + m * 16 + ((l >> 4) << 2) + j;
        const float dd = aH[m][j] + aM[m][j] * SCL;
        const float dist = fmaf(-2.0f, dd, cbn[k]);
        if (dist < bestd) { bestd = dist; best = k; }
      }
    }
  }

#pragma unroll
  for (int off = 16; off <= 32; off <<= 1) {
    const float d2 = __shfl_xor(bestd, off, 64);
    const int i2 = __shfl_xor(best, off, 64);
    if (d2 < bestd || (d2 == bestd && i2 < best)) { bestd = d2; best = i2; }
  }

#pragma unroll
  for (int i = 0; i < 16; i++) {
    const int d = (l >> 4) * 16 + i;
    zp[(size_t)d * 4096 + pos] = cb[d * 512 + best];
  }
}

// ---------------- conv 4x4 s2 p1 via MFMA fp16x2, LDS-staged weights ------
template<int CIN, int COT, bool RELU_OUT>
__global__ __launch_bounds__(256, 2) void conv4s2_mfma(
    const float* __restrict__ x, const ushort* __restrict__ wpk,
    const float* __restrict__ bias, float* __restrict__ y) {
  constexpr int nCh = CIN / 32, nM = COT / 16;
  constexpr int nStep = nCh * 2;
  constexpr int nTap = nStep * 8;
  __shared__ ushort act[2][2][2][66][40];   // 42,240 B
  __shared__ ushort wlds[2][8192];          // 32,768 B
  const int tid = threadIdx.x;
  const int l = tid & 63;
  const int wv = rfl(tid >> 6);
  const int ho = (blockIdx.x & 7) * 8 + (blockIdx.x >> 3);
  const int n = blockIdx.z;

  {
    uint* lp = (uint*)&act[0][0][0][0][0];
    for (int s = tid; s < 16 * 20; s += 256) {
      const int c = s / 20, w32 = s % 20;
      const int which = c & 1, rest = c >> 1;
      lp[(size_t)(rest * 66 + (which ? 65 : 0)) * 20 + w32] = 0;
    }
  }

  const float* xn = x + ((size_t)n * CIN) * 16384;

  float2 sreg[2][4][2];
  float rmask[2];
  auto LOADG = [&](int step) {
    const int ch = step >> 1, h = step & 1;
#pragma unroll
    for (int rr = 0; rr < 2; rr++) {
      const int ir = 2 * ho - 1 + 2 * h + rr;
      const bool ok = (ir >= 0) && (ir < 128);
      const int irc = ok ? ir : 0;
      rmask[rr] = ok ? 1.0f : 0.0f;
#pragma unroll
      for (int cc = 0; cc < 4; cc++) {
        const int ci0 = ch * 32 + cc * 8 + wv * 2;
        sreg[rr][cc][0] = *(const float2*)(xn + (size_t)ci0 * 16384 + irc * 128 + 2 * l);
        sreg[rr][cc][1] = *(const float2*)(xn + (size_t)(ci0 + 1) * 16384 + irc * 128 + 2 * l);
      }
    }
  };
  auto WRITE = [&]() {
    uint* base = (uint*)&act[0][0][0][0][0];
#pragma unroll
    for (int rr = 0; rr < 2; rr++) {
#pragma unroll
      for (int cc = 0; cc < 4; cc++) {
        const float e0 = sreg[rr][cc][0].x * rmask[rr], o0 = sreg[rr][cc][0].y * rmask[rr];
        const float e1 = sreg[rr][cc][1].x * rmask[rr], o1 = sreg[rr][cc][1].y * rmask[rr];
        const ushort he0 = f2h(e0), ho_0 = f2h(o0);
        const ushort he1 = f2h(e1), ho_1 = f2h(o1);
        const ushort le0 = f2h((e0 - h2f(he0)) * 2048.0f);
        const ushort lo0 = f2h((o0 - h2f(ho_0)) * 2048.0f);
        const ushort le1 = f2h((e1 - h2f(he1)) * 2048.0f);
        const ushort lo1 = f2h((o1 - h2f(ho_1)) * 2048.0f);
        const int u = cc * 4 + wv;
        const size_t sl20 = (size_t)(l + 1) * 20 + u;
        base[(size_t)((0 * 2 + rr) * 2 + 0) * 1320 + sl20] = pk(he0, he1);
        base[(size_t)((0 * 2 + rr) * 2 + 1) * 1320 + sl20] = pk(ho_0, ho_1);
        base[(size_t)((1 * 2 + rr) * 2 + 0) * 1320 + sl20] = pk(le0, le1);
        base[(size_t)((1 * 2 + rr) * 2 + 1) * 1320 + sl20] = pk(lo0, lo1);
      }
    }
  };
  auto STAGEW = [&](int t, int buf) {
    const ushort* src = wpk + (size_t)t * 8192;
    ushort* dst = &wlds[buf][0];
#pragma unroll
    for (int j = 0; j < 4; j++)
      async_copy16((const float*)(src + (j * 256 + tid) * 8),
                   (float*)(dst + (j * 256 + tid) * 8));
  };

  f32x4 accH[nM], accM[nM];
#pragma unroll
  for (int m = 0; m < nM; m++) {
    const int co = m * 16 + ((l >> 4) << 2);
    accH[m] = (f32x4){bias[co], bias[co + 1], bias[co + 2], bias[co + 3]};
    accM[m] = (f32x4){0.f, 0.f, 0.f, 0.f};
  }

  const int pb = wv * 16;
  const int sw = (16 * l) ^ ((l & 4) ? 8 : 0);
  STAGEW(0, 0);
  LOADG(0);
  int tcnt = 0;
  for (int step = 0; step < nStep; step++) {
    __syncthreads();
    WRITE();
    __syncthreads();
#pragma unroll
    for (int rr = 0; rr < 2; rr++) {
#pragma unroll
      for (int kw = 0; kw < 4; kw++) {
        if (!(rr == 0 && kw == 0)) __syncthreads();
        if (tcnt + 1 < nTap) STAGEW(tcnt + 1, (tcnt + 1) & 1);
        if (rr == 0 && kw == 0 && step + 1 < nStep) LOADG(step + 1);
        const ushort* wb = &wlds[tcnt & 1][0];
        const int eo = (kw == 0 || kw == 2) ? 1 : 0;
        const int sh = (kw == 0) ? 0 : (kw == 3) ? 2 : 1;
        const int sl = pb + (l & 15) + sh;
        const h16x8 bh = *(const h16x8*)(&act[0][rr][eo][sl][(l >> 4) * 8]);
        const h16x8 bl = *(const h16x8*)(&act[1][rr][eo][sl][(l >> 4) * 8]);
#pragma unroll
        for (int m = 0; m < nM; m++) {
          const h16x8 ah = *(const h16x8*)(wb + m * 1024 + sw);
          const h16x8 al = *(const h16x8*)(wb + m * 1024 + (sw ^ 8));
          accH[m] = __builtin_amdgcn_mfma_f32_16x16x32_f16(ah, bh, accH[m], 0, 0, 0);
          accM[m] = __builtin_amdgcn_mfma_f32_16x16x32_f16(al, bh, accM[m], 0, 0, 0);
          accM[m] = __builtin_amdgcn_mfma_f32_16x16x32_f16(ah, bl, accM[m], 0, 0, 0);
        }
        tcnt++;
      }
    }
  }

  const float SCL = 1.0f / 2048.0f;
  const int pos = pb + (l & 15);
  const int r4 = (l >> 4) << 2;
#pragma unroll
  for (int m = 0; m < nM; m++) {
    const int co = m * 16 + r4;
    float* yp = y + (((size_t)(n * COT + co)) * 64 + ho) * 64 + pos;
#pragma unroll
    for (int j = 0; j < 4; j++) {
      float v = accH[m][j] + accM[m][j] * SCL;
      if (RELU_OUT) v = fmaxf(v, 0.f);
      yp[(size_t)j * 4096] = v;
    }
  }
}

// ---------------- conv 3x3 s1 p1, MFMA fp16x2, 2 rows/block ---------------
// Block = output rows r0, r0+1 x all COT. Act: 2 planes x 4 input rows
// (rows share staging; each weight read feeds both rows' B-frags).
// Weight dbuf 2 x nM KB (TP=1, R29 slab layout). 48 MFMAs/barrier (nM=8).
// LDS: 42.2 + 2*nM*2 KB -> 74.2 KB (COT=128, 2 blocks/CU).
template<int CIN, int COT, bool RELU_IN>
__global__ __launch_bounds__(256, 2) void conv3_mfma2(
    const float* __restrict__ x, const ushort* __restrict__ wpk,
    const float* __restrict__ bias, float* __restrict__ y) {
  constexpr int nCh = CIN / 32, nM = COT / 16;
  constexpr int nTap = nCh * 9;
  __shared__ ushort act[2][4 * 66 * 40];    // 42,240 B
  __shared__ ushort wlds[2][nM * 1024];     // 2 x nM*2 KB
  const int tid = threadIdx.x;
  const int l = tid & 63;
  const int wv = rfl(tid >> 6);             // 0..3
  const int r0 = blockIdx.x * 2;            // output rows r0, r0+1
  const int n = blockIdx.z;

  // zero pad slots 0 and 65: 2 planes x 4 rows x 2 slots
  {
    uint* lp = (uint*)&act[0][0];
    for (int s = tid; s < 16 * 20; s += 256) {
      const int c = s / 20, w32 = s % 20;
      const int which = c & 1;
      const int rowrel = (c >> 1) & 3;
      const int plane  = c >> 3;
      lp[(size_t)(plane * 264 + rowrel * 66 + (which ? 65 : 0)) * 20 + w32] = 0;
    }
  }

  const float* xn = x + ((size_t)n * CIN) * 4096;

  float sreg[4][4][2];
  auto LOADG = [&](int ch) {
#pragma unroll
    for (int rr = 0; rr < 4; rr++) {
      const int ir = r0 - 1 + rr;
      const bool ok = (ir >= 0) && (ir < 64);
#pragma unroll
      for (int cc = 0; cc < 4; cc++) {
        const int ci0 = ch * 32 + cc * 8 + wv * 2;
        sreg[rr][cc][0] = ok ? xn[((size_t)ci0 * 64 + ir) * 64 + l] : 0.f;
        sreg[rr][cc][1] = ok ? xn[((size_t)(ci0 + 1) * 64 + ir) * 64 + l] : 0.f;
      }
    }
  };
  auto WRITE = [&]() {
    uint* ph = (uint*)&act[0][0];
    uint* pl = (uint*)&act[1][0];
#pragma unroll
    for (int rr = 0; rr < 4; rr++) {
#pragma unroll
      for (int cc = 0; cc < 4; cc++) {
        float v0 = sreg[rr][cc][0], v1 = sreg[rr][cc][1];
        if (RELU_IN) { v0 = fmaxf(v0, 0.f); v1 = fmaxf(v1, 0.f); }
        const ushort h0 = f2h(v0), h1 = f2h(v1);
        const ushort m0 = f2h((v0 - h2f(h0)) * 2048.0f);
        const ushort m1 = f2h((v1 - h2f(h1)) * 2048.0f);
        const int idx = (rr * 66 + (l + 1)) * 20 + cc * 4 + wv;   // u32 index
        ph[idx] = (uint)h0 | ((uint)h1 << 16);
        pl[idx] = (uint)m0 | ((uint)m1 << 16);
      }
    }
  };
  auto STAGEW = [&](int t, int buf) {
    const ushort* src = wpk + (size_t)t * (nM * 1024);
    ushort* dst = &wlds[buf][0];
#pragma unroll
    for (int j = 0; j < nM / 2; j++)
      async_copy16((const float*)(src + (j * 256 + tid) * 8),
                   (float*)(dst + (j * 256 + tid) * 8));
  };

  f32x4 accH[2][nM], accM[2][nM];
#pragma unroll
  for (int m = 0; m < nM; m++) {
    const int co = m * 16 + ((l >> 4) << 2);
    const f32x4 b4 = (f32x4){bias[co], bias[co + 1], bias[co + 2], bias[co + 3]};
#pragma unroll
    for (int ro = 0; ro < 2; ro++) {
      accH[ro][m] = b4;
      accM[ro][m] = (f32x4){0.f, 0.f, 0.f, 0.f};
    }
  }

  const int pb = wv * 16;
  const int sw = (16 * l) ^ ((l & 4) ? 8 : 0);
  STAGEW(0, 0);
  LOADG(0);
  int tcnt = 0;
  for (int ch = 0; ch < nCh; ch++) {
    __syncthreads();                 // act readers done; DMA + loads drained
    WRITE();                         // act(ch): 4 rows
    __syncthreads();                 // act visible; = tap barrier for tap 0
#pragma unroll
    for (int kh = 0; kh < 3; kh++) {
#pragma unroll
      for (int kw = 0; kw < 3; kw++) {
        if (!(kh == 0 && kw == 0)) __syncthreads();   // tap barrier
        if (tcnt + 1 < nTap) STAGEW(tcnt + 1, (tcnt + 1) & 1);
        if (kh == 0 && kw == 0 && ch + 1 < nCh) LOADG(ch + 1);
        const ushort* wb = &wlds[tcnt & 1][0];
        // B-frags for both output rows (staged row = ro + kh)
        h16x8 bh[2], bl[2];
#pragma unroll
        for (int ro = 0; ro < 2; ro++) {
          const int slot = (ro + kh) * 66 + pb + (l & 15) + kw;
          bh[ro] = *(const h16x8*)(&act[0][0] + slot * 40 + (l >> 4) * 8);
          bl[ro] = *(const h16x8*)(&act[1][0] + slot * 40 + (l >> 4) * 8);
        }
#pragma unroll
        for (int m = 0; m < nM; m++) {
          const h16x8 ah = *(const h16x8*)(wb + m * 1024 + sw);
          const h16x8 al = *(const h16x8*)(wb + m * 1024 + (sw ^ 8));
#pragma unroll
          for (int ro = 0; ro < 2; ro++) {
            accH[ro][m] = __builtin_amdgcn_mfma_f32_16x16x32_f16(ah, bh[ro], accH[ro][m], 0, 0, 0);
            accM[ro][m] = __builtin_amdgcn_mfma_f32_16x16x32_f16(al, bh[ro], accM[ro][m], 0, 0, 0);
            accM[ro][m] = __builtin_amdgcn_mfma_f32_16x16x32_f16(ah, bl[ro], accM[ro][m], 0, 0, 0);
          }
        }
        tcnt++;
      }
    }
  }

  const float SCL = 1.0f / 2048.0f;
  const int pos = pb + (l & 15);
  const int r4 = (l >> 4) << 2;
#pragma unroll
  for (int ro = 0; ro < 2; ro++) {
#pragma unroll
    for (int m = 0; m < nM; m++) {
      const int co = m * 16 + r4;
      float* yp = y + (((size_t)(n * COT + co)) * 64 + (r0 + ro)) * 64 + pos;
#pragma unroll
      for (int j = 0; j < 4; j++)
        yp[(size_t)j * 4096] = accH[ro][m][j] + accM[ro][m][j] * SCL;
    }
  }
}

// ---------------- ConvTranspose 4x4 s2 p1, MFMA fp16x2, 2 taps/phase ------
template<int CIN, int COT, bool RELU_OUT>
__global__ __launch_bounds__(256, 2) void convt_mfma(
    const float* __restrict__ x, const ushort* __restrict__ wpk,
    const float* __restrict__ bias, float* __restrict__ y) {
  constexpr int nCh = CIN / 32, nM = COT / 16;
  constexpr int nPair = nCh * 8;
  __shared__ ushort act[2][3 * 66 * 40];    // 31,680 B
  __shared__ ushort wlds[2][2 * nM * 1024]; // 2 x 16 KB
  const int tid = threadIdx.x;
  const int l = tid & 63;
  const int wv = rfl(tid >> 6);
  const int a = blockIdx.x;                 // input row 0..63
  const int n = blockIdx.z;

  {
    uint* lp = (uint*)&act[0][0];
    for (int s = tid; s < 12 * 20; s += 256) {
      const int c = s / 20, w32 = s % 20;
      const int which = c & 1;
      const int rowrel = (c >> 1) % 3;
      const int plane  = (c >> 1) / 3;
      lp[(size_t)(plane * 198 + rowrel * 66 + (which ? 65 : 0)) * 20 + w32] = 0;
    }
  }

  const float* xn = x + ((size_t)n * CIN) * 4096;

  float sreg[3][4][2];
  auto LOADG = [&](int ch) {
#pragma unroll
    for (int rr = 0; rr < 3; rr++) {
      const int ir = a - 1 + rr;
      const bool ok = (ir >= 0) && (ir < 64);
#pragma unroll
      for (int cc = 0; cc < 4; cc++) {
        const int ci0 = ch * 32 + cc * 8 + wv * 2;
        sreg[rr][cc][0] = ok ? xn[((size_t)ci0 * 64 + ir) * 64 + l] : 0.f;
        sreg[rr][cc][1] = ok ? xn[((size_t)(ci0 + 1) * 64 + ir) * 64 + l] : 0.f;
      }
    }
  };
  auto WRITE = [&]() {
    uint* ph = (uint*)&act[0][0];
    uint* pl = (uint*)&act[1][0];
#pragma unroll
    for (int rr = 0; rr < 3; rr++) {
#pragma unroll
      for (int cc = 0; cc < 4; cc++) {
        const float v0 = sreg[rr][cc][0], v1 = sreg[rr][cc][1];
        const ushort h0 = f2h(v0), h1 = f2h(v1);
        const ushort m0 = f2h((v0 - h2f(h0)) * 2048.0f);
        const ushort m1 = f2h((v1 - h2f(h1)) * 2048.0f);
        const int idx = (rr * 66 + (l + 1)) * 20 + cc * 4 + wv;
        ph[idx] = (uint)h0 | ((uint)h1 << 16);
        pl[idx] = (uint)m0 | ((uint)m1 << 16);
      }
    }
  };
  auto STAGEW2 = [&](int p, int buf) {
    const ushort* src = wpk + (size_t)p * (2 * nM * 1024);
    ushort* dst = &wlds[buf][0];
#pragma unroll
    for (int j = 0; j < nM; j++)
      async_copy16((const float*)(src + (j * 256 + tid) * 8),
                   (float*)(dst + (j * 256 + tid) * 8));
  };

  f32x4 aH[4][nM], aM[4][nM];
#pragma unroll
  for (int m = 0; m < nM; m++) {
    const int co = m * 16 + ((l >> 4) << 2);
    const f32x4 b4 = (f32x4){bias[co], bias[co + 1], bias[co + 2], bias[co + 3]};
#pragma unroll
    for (int o = 0; o < 4; o++) { aH[o][m] = b4; aM[o][m] = (f32x4){0.f,0.f,0.f,0.f}; }
  }

  const int pb = wv * 16;
  const int sw = (16 * l) ^ ((l & 4) ? 8 : 0);
  STAGEW2(0, 0);
  LOADG(0);
  int pcnt = 0;

#define CT_TAP(WOFS, RR, DD, OIDX) {                                          \
    const int slot = (RR) * 66 + pb + (l & 15) + 1 + (DD);                    \
    const h16x8 bh = *(const h16x8*)(&act[0][0] + slot * 40 + (l >> 4) * 8);  \
    const h16x8 bl = *(const h16x8*)(&act[1][0] + slot * 40 + (l >> 4) * 8);  \
    _Pragma("unroll")                                                         \
    for (int m = 0; m < nM; m++) {                                            \
      const h16x8 ah = *(const h16x8*)(wb + (WOFS) + m * 1024 + sw);          \
      const h16x8 al = *(const h16x8*)(wb + (WOFS) + m * 1024 + (sw ^ 8));    \
      aH[OIDX][m] = __builtin_amdgcn_mfma_f32_16x16x32_f16(ah, bh, aH[OIDX][m], 0, 0, 0); \
      aM[OIDX][m] = __builtin_amdgcn_mfma_f32_16x16x32_f16(al, bh, aM[OIDX][m], 0, 0, 0); \
      aM[OIDX][m] = __builtin_amdgcn_mfma_f32_16x16x32_f16(ah, bl, aM[OIDX][m], 0, 0, 0); \
    }}
#define CT_PHASE(RRA, DDA, OA, RRB, DDB, OB) {                                \
    if (!first) __syncthreads();                                              \
    first = false;                                                            \
    if (pcnt + 1 < nPair) STAGEW2(pcnt + 1, (pcnt + 1) & 1);                  \
    if (doLoad) { if (ch + 1 < nCh) LOADG(ch + 1); doLoad = false; }          \
    const ushort* wb = &wlds[pcnt & 1][0];                                    \
    CT_TAP(0, RRA, DDA, OA)                                                   \
    CT_TAP(nM * 1024, RRB, DDB, OB)                                           \
    pcnt++; }

  for (int ch = 0; ch < nCh; ch++) {
    __syncthreads();                 // prev phase done; DMA + loads drained
    WRITE();                         // act(ch)
    __syncthreads();                 // act visible; = barrier for phase 0
    bool first = true, doLoad = true;
    CT_PHASE(0, -1, 0,  0,  0, 0)
    CT_PHASE(0,  0, 1,  0, +1, 1)
    CT_PHASE(1, -1, 0,  1, -1, 2)
    CT_PHASE(1,  0, 0,  1,  0, 1)
    CT_PHASE(1,  0, 2,  1,  0, 3)
    CT_PHASE(1, +1, 1,  1, +1, 3)
    CT_PHASE(2, -1, 2,  2,  0, 2)
    CT_PHASE(2,  0, 3,  2, +1, 3)
  }
#undef CT_TAP
#undef CT_PHASE

  const float SCL = 1.0f / 2048.0f;
  const int b = pb + (l & 15);
  const int oh0 = 2 * a;
  const int r4 = (l >> 4) << 2;
#pragma unroll
  for (int m = 0; m < nM; m++) {
    const int co = m * 16 + r4;
#pragma unroll
    for (int j = 0; j < 4; j++) {
      float v0e = aH[0][m][j] + aM[0][m][j] * SCL;
      float v0o = aH[1][m][j] + aM[1][m][j] * SCL;
      float v1e = aH[2][m][j] + aM[2][m][j] * SCL;
      float v1o = aH[3][m][j] + aM[3][m][j] * SCL;
      if (RELU_OUT) {
        v0e = fmaxf(v0e, 0.f); v0o = fmaxf(v0o, 0.f);
        v1e = fmaxf(v1e, 0.f); v1o = fmaxf(v1o, 0.f);
      }
      float* row0 = y + (((size_t)(n * COT + co + j)) * 128 + oh0) * 128;
      ((float2*)row0)[b] = make_float2(v0e, v0o);
      ((float2*)(row0 + 128))[b] = make_float2(v1e, v1o);
    }
  }
}

// ---------------- conv 4x4 stride2 pad1 (generic, used for conv0) ---------
template<int CIN, int COT, bool RELU_OUT, int OW>
__global__ __launch_bounds__(256) void conv4s2_row(
    const float* __restrict__ x, const float* __restrict__ w,
    const float* __restrict__ bias, float* __restrict__ y,
    int Hout, int Cout) {
  const int Win = OW * 2, Hin = Hout * 2;
  const int t = blockIdx.x * 256 + threadIdx.x;
  const int wo = t & (OW - 1);
  const int ho = rfl(t / OW);
  const int co0 = blockIdx.y * COT, n = blockIdx.z;

  float acc[COT];
#pragma unroll
  for (int u = 0; u < COT; u++) acc[u] = bias[co0 + u];

  const int iw0 = 2 * wo - 1;
  const int cA = iw0 < 0 ? 0 : iw0;
  const bool mA = iw0 >= 0;
  const int cD = (iw0 + 3 < Win) ? iw0 + 3 : Win - 1;
  const bool mD = iw0 + 3 < Win;

  for (int ci = 0; ci < CIN; ci++) {
    const float* xp = x + ((size_t)(n * CIN + ci)) * Hin * Win;
    const float* wp = w + ((size_t)(co0 * CIN + ci)) * 16;
#pragma unroll
    for (int kh = 0; kh < 4; kh++) {
      const int ih = 2 * ho - 1 + kh;
      if (ih >= 0 && ih < Hin) {
        const float* row = xp + (size_t)ih * Win;
        float x0 = row[cA];      x0 = mA ? x0 : 0.f;
        float x1 = row[iw0 + 1];
        float x2 = row[iw0 + 2];
        float x3 = row[cD];      x3 = mD ? x3 : 0.f;
#pragma unroll
        for (int u = 0; u < COT; u++) {
          const float* wr = wp + u * CIN * 16 + kh * 4;
          acc[u] = fmaf(x0, wr[0], acc[u]);
          acc[u] = fmaf(x1, wr[1], acc[u]);
          acc[u] = fmaf(x2, wr[2], acc[u]);
          acc[u] = fmaf(x3, wr[3], acc[u]);
        }
      }
    }
  }
#pragma unroll
  for (int u = 0; u < COT; u++) {
    float v = acc[u];
    if (RELU_OUT) v = fmaxf(v, 0.f);
    y[(((size_t)(n * Cout + co0 + u)) * Hout + ho) * OW + wo] = v;
  }
}

// ---------------- conv 1x1 v4: 4 positions per thread ---------------------
template<int CIN, int COT, bool RELU_IN, bool ACCUM, bool RELU_OUT>
__global__ __launch_bounds__(256) void conv1x1_v4(
    const float* __restrict__ x, const float* __restrict__ w,
    const float* __restrict__ bias, float* __restrict__ y,
    int HW, int Cout) {
  const int p = (blockIdx.x * 256 + threadIdx.x) * 4;
  const int co0 = blockIdx.y * COT, n = blockIdx.z;

  float4 acc[COT];
#pragma unroll
  for (int u = 0; u < COT; u++) {
    const float b = bias[co0 + u];
    acc[u] = make_float4(b, b, b, b);
  }
  for (int ci = 0; ci < CIN; ci++) {
    float4 xv = *(const float4*)&x[((size_t)(n * CIN + ci)) * HW + p];
    if (RELU_IN) {
      xv.x = fmaxf(xv.x, 0.f); xv.y = fmaxf(xv.y, 0.f);
      xv.z = fmaxf(xv.z, 0.f); xv.w = fmaxf(xv.w, 0.f);
    }
#pragma unroll
    for (int u = 0; u < COT; u++) {
      const float wv = w[(co0 + u) * CIN + ci];
      acc[u].x = fmaf(xv.x, wv, acc[u].x);
      acc[u].y = fmaf(xv.y, wv, acc[u].y);
      acc[u].z = fmaf(xv.z, wv, acc[u].z);
      acc[u].w = fmaf(xv.w, wv, acc[u].w);
    }
  }
#pragma unroll
  for (int u = 0; u < COT; u++) {
    float4* yp = (float4*)&y[((size_t)(n * Cout + co0 + u)) * HW + p];
    float4 r = acc[u];
    if (ACCUM) {
      float4 h = *yp;
      r.x += h.x; r.y += h.y; r.z += h.z; r.w += h.w;
    }
    if (RELU_OUT) {
      r.x = fmaxf(r.x, 0.f); r.y = fmaxf(r.y, 0.f);
      r.z = fmaxf(r.z, 0.f); r.w = fmaxf(r.w, 0.f);
    }
    *yp = r;
  }
}

// ---------------- ConvTranspose 4x4 s2 p1 (generic, used for up1) ---------
template<int CIN, int COT, bool RELU_IN, bool RELU_OUT, int WH>
__global__ __launch_bounds__(256) void convt_row(
    const float* __restrict__ x, const float* __restrict__ w,
    const float* __restrict__ bias, float* __restrict__ y,
    int Hin, int Cout) {
  const int Hout = Hin * 2;
  const int t = blockIdx.x * 256 + threadIdx.x;
  const int a = t & (WH - 1);
  const int oh = rfl(t / WH);
  const int co0 = blockIdx.y * COT, n = blockIdx.z;

  float acc0[COT], acc1[COT];
#pragma unroll
  for (int u = 0; u < COT; u++) { acc0[u] = bias[co0 + u]; acc1[u] = bias[co0 + u]; }

  const int cm = a > 0 ? a - 1 : 0;
  const bool mm = a > 0;
  const int cp = a < WH - 1 ? a + 1 : WH - 1;
  const bool mp = a < WH - 1;

  const int kh0 = (oh + 1) & 1;
#pragma unroll
  for (int dh = 0; dh < 2; dh++) {
    const int kh = kh0 + 2 * dh;
    const int ih = (oh + 1 - kh) >> 1;
    if (ih >= 0 && ih < Hin) {
      for (int ci = 0; ci < CIN; ci++) {
        const float* row = x + (((size_t)(n * CIN + ci)) * Hin + ih) * WH;
        float x0  = row[a];
        float xm1 = row[cm];  xm1 = mm ? xm1 : 0.f;
        float xp1 = row[cp];  xp1 = mp ? xp1 : 0.f;
        if (RELU_IN) {
          x0 = fmaxf(x0, 0.f); xm1 = fmaxf(xm1, 0.f); xp1 = fmaxf(xp1, 0.f);
        }
        const float* wp = w + ((size_t)(ci * Cout + co0)) * 16 + kh * 4;
#pragma unroll
        for (int u = 0; u < COT; u++) {
          const float* wr = wp + u * 16;
          acc0[u] = fmaf(x0,  wr[1], acc0[u]);
          acc0[u] = fmaf(xm1, wr[3], acc0[u]);
          acc1[u] = fmaf(xp1, wr[0], acc1[u]);
          acc1[u] = fmaf(x0,  wr[2], acc1[u]);
        }
      }
    }
  }
#pragma unroll
  for (int u = 0; u < COT; u++) {
    float v0 = acc0[u], v1 = acc1[u];
    if (RELU_OUT) { v0 = fmaxf(v0, 0.f); v1 = fmaxf(v1, 0.f); }
    float* row = y + (((size_t)(n * Cout + co0 + u)) * Hout + oh) * (2 * WH);
    ((float2*)row)[a] = make_float2(v0, v1);
  }
}

// -------------------------------------------------------------------------
extern "C" void kernel_launch(void* const* d_in, const int* in_sizes, int n_in,
                              void* d_out, int out_size, void* d_ws, size_t ws_size,
                              hipStream_t stream) {
  const float* x          = (const float*)d_in[0];
  const float* enc_w0     = (const float*)d_in[1];
  const float* enc_b0     = (const float*)d_in[2];
  const float* enc_w1     = (const float*)d_in[3];
  const float* enc_b1     = (const float*)d_in[4];
  const float* enc_wf     = (const float*)d_in[5];
  const float* enc_bf     = (const float*)d_in[6];
  const float* enc_res_w1 = (const float*)d_in[7];
  const float* enc_res_b1 = (const float*)d_in[8];
  const float* enc_res_w2 = (const float*)d_in[9];
  const float* enc_res_b2 = (const float*)d_in[10];
  const float* pre_w      = (const float*)d_in[11];
  const float* pre_b      = (const float*)d_in[12];
  const float* codebook   = (const float*)d_in[13];
  const float* dec_w      = (const float*)d_in[14];
  const float* dec_b      = (const float*)d_in[15];
  const float* dec_res_w1 = (const float*)d_in[16];
  const float* dec_res_b1 = (const float*)d_in[17];
  const float* dec_res_w2 = (const float*)d_in[18];
  const float* dec_res_b2 = (const float*)d_in[19];
  const float* up_w0      = (const float*)d_in[20];
  const float* up_b0      = (const float*)d_in[21];
  const float* up_w1      = (const float*)d_in[22];
  const float* up_b1      = (const float*)d_in[23];
  float* out = (float*)d_out;

  float* A = (float*)d_ws;         // 16,777,216 floats (64 MB)
  float* B = A + 16777216;         //  8,388,608 floats (32 MB)
  float* C = B + 8388608;          //  8,388,608 floats (32 MB)
  // conv3 weight packs + VQ packs in A's tail (floats 8.39M..). Written
  // after conv1 (A dead then); later A writers stay below 4.2M floats;
  // dead before up0 rewrites A.
  ushort* wpkF  = (ushort*)(A + 8388608);          // convf  294912 ush
  ushort* wpkEa = wpkF  + 294912;                  // enc r1a 73728
  ushort* wpkEb = wpkEa + 73728;                   // enc r1b 73728
  ushort* wpkD  = wpkEb + 73728;                   // dec    147456
  ushort* wpkDa = wpkD  + 147456;                  // dec r1a 73728
  ushort* wpkDb = wpkDa + 73728;                   // dec r1b 73728
  ushort* cbpk  = wpkDb + 73728;                   // vq cb pack 131072 ush
  float*  cbn   = (float*)(cbpk + 131072);         // 512 floats
  // C head: conv1 pack (dead once conv1 ran; convf then overwrites C),
  // later reused for up0 pack (written after pre, C dead then).
  ushort* wpk1  = (ushort*)C;                      // 262144 ush (512 KB)
  ushort* wpkT  = wpk1 + 262144;                   // 262144 ush

  const dim3 blk(256);
  const int N = 16;

  // --- conv1 weight prepack into C head (C untouched until convf) ---
  prep_w4s<64, 128><<<dim3(64), blk, 0, stream>>>(enc_w1, wpk1);

  // --- Encoder ---
  conv4s2_row<3, 16, true, 128><<<dim3(64, 4, N), blk, 0, stream>>>(
      x, enc_w0, enc_b0, A, 128, 64);
  // conv1: MFMA stride-2 implicit GEMM, LDS-staged weights, A -> B
  conv4s2_mfma<64, 128, true><<<dim3(64, 1, N), blk, 0, stream>>>(
      A, wpk1, enc_b1, B);

  // --- prepacks into A's tail (A dead: conv1 consumed it) ---
  prep_w3s<128, 128><<<dim3(72), blk, 0, stream>>>(enc_wf, wpkF);
  prep_w3s<128, 32><<<dim3(18), blk, 0, stream>>>(enc_res_w1, wpkEa);
  prep_w3s<128, 32><<<dim3(18), blk, 0, stream>>>(
      enc_res_w1 + (size_t)32 * 128 * 9, wpkEb);
  prep_w3s<64, 128><<<dim3(36), blk, 0, stream>>>(dec_w, wpkD);
  prep_w3s<128, 32><<<dim3(18), blk, 0, stream>>>(dec_res_w1, wpkDa);
  prep_w3s<128, 32><<<dim3(18), blk, 0, stream>>>(
      dec_res_w1 + (size_t)32 * 128 * 9, wpkDb);
  prep_cb<<<dim3(16), blk, 0, stream>>>(codebook, cbpk);
  cvt_cbn<<<dim3(2), blk, 0, stream>>>(codebook, cbn);

  // convf: MFMA, 2 rows/block (input B already relu'd)
  conv3_mfma2<128, 128, false><<<dim3(32, 1, N), blk, 0, stream>>>(
      B, wpkF, enc_bf, C);
  // enc res stack on C
  conv3_mfma2<128, 32, true><<<dim3(32, 1, N), blk, 0, stream>>>(
      C, wpkEa, enc_res_b1, A);
  conv1x1_v4<32, 8, true, true, false><<<dim3(4, 16, N), blk, 0, stream>>>(
      A, enc_res_w2, enc_res_b2, C, 4096, 128);
  conv3_mfma2<128, 32, true><<<dim3(32, 1, N), blk, 0, stream>>>(
      C, wpkEb, enc_res_b1 + 32, A);
  conv1x1_v4<32, 8, true, true, true><<<dim3(4, 16, N), blk, 0, stream>>>(
      A, enc_res_w2 + (size_t)128 * 32, enc_res_b2 + 128, C, 4096, 128);
  // pre: C already relu'd -> z in A
  conv1x1_v4<128, 8, false, false, false><<<dim3(4, 8, N), blk, 0, stream>>>(
      C, pre_w, pre_b, A, 4096, 64);

  // --- up0 weight prepack into C (C dead after pre) ---
  prep_wts<128, 64><<<dim3(64), blk, 0, stream>>>(up_w0, wpkT);

  // --- VQ (in-place on A) via MFMA ---
  vq_mfma<<<dim3(1024), blk, 0, stream>>>(codebook, cbpk, cbn, A);

  // --- Decoder ---
  conv3_mfma2<64, 128, false><<<dim3(32, 1, N), blk, 0, stream>>>(
      A, wpkD, dec_b, B);
  conv3_mfma2<128, 32, true><<<dim3(32, 1, N), blk, 0, stream>>>(
      B, wpkDa, dec_res_b1, A);
  conv1x1_v4<32, 8, true, true, false><<<dim3(4, 16, N), blk, 0, stream>>>(
      A, dec_res_w2, dec_res_b2, B, 4096, 128);
  conv3_mfma2<128, 32, true><<<dim3(32, 1, N), blk, 0, stream>>>(
      B, wpkDb, dec_res_b1 + 32, A);
  conv1x1_v4<32, 8, true, true, true><<<dim3(4, 16, N), blk, 0, stream>>>(
      A, dec_res_w2 + (size_t)128 * 32, dec_res_b2 + 128, B, 4096, 128);
  // up0: MFMA ConvTranspose, LDS-staged weights, B (relu'd) -> A, ReLU out
  convt_mfma<128, 64, true><<<dim3(64, 1, N), blk, 0, stream>>>(
      B, wpkT, up_b0, A);
  // up1: A -> out(16,3,256,256)
  convt_row<64, 3, false, false, 128><<<dim3(128, 1, N), blk, 0, stream>>>(
      A, up_w1, up_b1, out, 128, 3);
}

// Round 15
// 725.457 us; speedup vs baseline: 1.0890x; 1.0890x over previous
//
#include <hip/hip_runtime.h>
#include <math.h>

// -------------------------------------------------------------------------
// VQ-VAE forward, fp32, round 35: conv3 2-rows/block + COT tiling (fixes
// R14's register spill).
//  - R14 REGRESSED (760->790): 2-row at nM=8 needs 128 acc VGPRs alone ->
//    spilled (WRITE_SIZE 32->88 MB = scratch). Fix: TILE param; nMt=TILE/16;
//    convf/dec TILE=64 -> acc 64 VGPRs (no spill), 58 KB LDS, weight-LDS
//    traffic per MFMA halved vs R13 and act conversion halved per row.
//    res TILE=32. Testable: WRITE_SIZE must drop back to ~33 MB.
//  - Everything else identical to R13/R14 common base.
// Remaining fp32 VALU: conv0, 1x1s, up1.
// -------------------------------------------------------------------------

#define DEV __device__ __forceinline__

DEV int rfl(int v) { return __builtin_amdgcn_readfirstlane(v); }

DEV void async_copy16(const float* g, float* l) {
  __builtin_amdgcn_global_load_lds(
      (const __attribute__((address_space(1))) void*)g,
      (__attribute__((address_space(3))) void*)l, 16, 0, 0);
}

typedef __attribute__((ext_vector_type(8))) _Float16 h16x8;
typedef __attribute__((ext_vector_type(4))) float f32x4;

DEV ushort f2h(float f) {
  _Float16 h = (_Float16)f;
  return __builtin_bit_cast(ushort, h);
}
DEV float h2f(ushort u) { return (float)__builtin_bit_cast(_Float16, u); }
DEV uint pk(ushort a, ushort b) { return (uint)a | ((uint)b << 16); }

// ---------------- weight prepack for conv3 (LDS-staged) -------------------
// nCh*9 slabs of nM*1024 ush, slab sid = ch*9 + kh*3 + kw (execution order).
// Within slab: m, lane l: ah 8 ush at m*1024 + (16l ^ s(l)), al at ^8,
// s(l) = (l&4) ? 8 : 0 (bank-balanced; linear DMA preserves it).
template<int CIN, int COT>
__global__ __launch_bounds__(256) void prep_w3s(
    const float* __restrict__ w, ushort* __restrict__ wpk) {
  constexpr int nCh = CIN / 32, nM = COT / 16;
  const int t = blockIdx.x * 256 + threadIdx.x;
  if (t >= 9 * nCh * nM * 64) return;
  const int l = t & 63;
  const int m = (t >> 6) % nM;
  const int sid = t / (64 * nM);
  const int ch = sid / 9, khkw = sid % 9;
  const int co = m * 16 + (l & 15);
  const int k8 = (l >> 4) * 8;
  const int sw = (16 * l) ^ ((l & 4) ? 8 : 0);
  ushort* slab = wpk + (size_t)sid * (nM * 1024) + m * 1024;
#pragma unroll
  for (int i = 0; i < 8; i++) {
    const int ci = ch * 32 + k8 + i;
    const float v = w[((size_t)co * CIN + ci) * 9 + khkw];
    const ushort hi = f2h(v);
    slab[sw + i]       = hi;
    slab[(sw ^ 8) + i] = f2h((v - h2f(hi)) * 2048.0f);
  }
}

// ---------------- weight prepack for conv4s2_mfma (LDS-staged) ------------
template<int CIN, int COT>
__global__ __launch_bounds__(256) void prep_w4s(
    const float* __restrict__ w, ushort* __restrict__ wpk) {
  const int t = blockIdx.x * 256 + threadIdx.x;   // 32*8*64 = 16384
  if (t >= 16384) return;
  const int l = t & 63;
  const int m = (t >> 6) & 7;
  const int sid = t >> 9;
  const int step = sid >> 3, rr = (sid >> 2) & 1, kw = sid & 3;
  const int ch = step >> 1, h = step & 1;
  const int kh = 2 * h + rr;
  const int tap = kh * 4 + kw;
  const int co = m * 16 + (l & 15);
  const int k8 = (l >> 4) * 8;
  const int sw = (16 * l) ^ ((l & 4) ? 8 : 0);
  ushort* slab = wpk + (size_t)sid * 8192 + m * 1024;
#pragma unroll
  for (int i = 0; i < 8; i++) {
    const int ci = ch * 32 + k8 + i;
    const float v = w[((size_t)co * CIN + ci) * 16 + tap];
    const ushort hi = f2h(v);
    slab[sw + i]       = hi;
    slab[(sw ^ 8) + i] = f2h((v - h2f(hi)) * 2048.0f);
  }
}

// ---------------- weight prepack for convt_mfma (LDS-staged) --------------
template<int CIN, int COT>
__global__ __launch_bounds__(256) void prep_wts(
    const float* __restrict__ w, ushort* __restrict__ wpk) {
  constexpr int nCh = CIN / 32, nM = COT / 16;
  const int t = blockIdx.x * 256 + threadIdx.x;
  if (t >= 16 * nCh * nM * 64) return;
  const int l = t & 63;
  const int m = (t >> 6) % nM;
  const int sid = t / (64 * nM);
  const int ch = sid >> 4, idx = sid & 15;
  const int ord[16] = {15, 13, 14, 12, 7, 11, 5, 6, 9, 10, 4, 8, 3, 1, 2, 0};
  const int tap = ord[idx];
  const int kh = tap >> 2, kw = tap & 3;
  const int co = m * 16 + (l & 15);
  const int k8 = (l >> 4) * 8;
  const int sw = (16 * l) ^ ((l & 4) ? 8 : 0);
  ushort* slab = wpk + (size_t)sid * (nM * 1024) + m * 1024;
#pragma unroll
  for (int i = 0; i < 8; i++) {
    const int ci = ch * 32 + k8 + i;
    const float v = w[(((size_t)ci * COT + co) * 4 + kh) * 4 + kw];
    const ushort hi = f2h(v);
    slab[sw + i]       = hi;
    slab[(sw ^ 8) + i] = f2h((v - h2f(hi)) * 2048.0f);
  }
}

// ---------------- codebook prepack for vq_mfma ----------------------------
__global__ __launch_bounds__(256) void prep_cb(
    const float* __restrict__ cb, ushort* __restrict__ cbpk) {
  const int t = blockIdx.x * 256 + threadIdx.x;   // 4096
  const int l = t & 63;
  const int m = (t >> 6) & 31;
  const int c = t >> 11;
  const int entry = m * 16 + (l & 15);
  ushort* o = cbpk + (size_t)t * 16;
#pragma unroll
  for (int i = 0; i < 8; i++) {
    const int d = c * 32 + (l >> 4) * 8 + i;
    const float v = cb[d * 512 + entry];
    const ushort hi = f2h(v);
    o[i]     = hi;
    o[8 + i] = f2h((v - h2f(hi)) * 2048.0f);
  }
}

// ---------------- codebook norms (fp64 accum -> fp32), once ---------------
__global__ __launch_bounds__(256) void cvt_cbn(
    const float* __restrict__ cb, float* __restrict__ cbn) {
  const int k = blockIdx.x * 256 + threadIdx.x;   // 0..511
  if (k >= 512) return;
  double s = 0.0;
  for (int d = 0; d < 64; d++) {
    const double c = (double)cb[d * 512 + k];
    s = fma(c, c, s);
  }
  cbn[k] = (float)s;
}

// ---------------- VQ via MFMA fp16x2: argmin + in-place quantize ----------
__global__ __launch_bounds__(256) void vq_mfma(
    const float* __restrict__ cb, const ushort* __restrict__ cbpk,
    const float* __restrict__ cbn, float* __restrict__ zq) {
  const int tid = threadIdx.x;
  const int l = tid & 63;
  const int w = rfl(tid >> 6);
  const int n = blockIdx.x >> 6, row = blockIdx.x & 63;
  float* zp = zq + (size_t)n * 262144 + row * 64;   // [d][64rows][64cols]
  const int pos = w * 16 + (l & 15);

  h16x8 zh[2], zl[2];
#pragma unroll
  for (int c = 0; c < 2; c++) {
#pragma unroll
    for (int i = 0; i < 8; i++) {
      const int d = c * 32 + (l >> 4) * 8 + i;
      const float v = zp[(size_t)d * 4096 + pos];
      const _Float16 h = (_Float16)v;
      zh[c][i] = h;
      zl[c][i] = (_Float16)((v - (float)h) * 2048.0f);
    }
  }

  const float SCL = 1.0f / 2048.0f;
  float bestd = 1e30f;
  int best = 0;
  for (int grp = 0; grp < 4; grp++) {
    f32x4 aH[8], aM[8];
#pragma unroll
    for (int m = 0; m < 8; m++) {
      aH[m] = (f32x4){0.f, 0.f, 0.f, 0.f};
      aM[m] = (f32x4){0.f, 0.f, 0.f, 0.f};
    }
#pragma unroll
    for (int c = 0; c < 2; c++) {
#pragma unroll
      for (int m = 0; m < 8; m++) {
        const ushort* ap = cbpk + ((size_t)(c * 32 + grp * 8 + m) * 64 + l) * 16;
        const h16x8 ah = *(const h16x8*)ap;
        const h16x8 al = *(const h16x8*)(ap + 8);
        aH[m] = __builtin_amdgcn_mfma_f32_16x16x32_f16(ah, zh[c], aH[m], 0, 0, 0);
        aM[m] = __builtin_amdgcn_mfma_f32_16x16x32_f16(al, zh[c], aM[m], 0, 0, 0);
        aM[m] = __builtin_amdgcn_mfma_f32_16x16x32_f16(ah, zl[c], aM[m], 0, 0, 0);
      }
    }
#pragma unroll
    for (int m = 0; m < 8; m++) {
#pragma unroll
      for (int j = 0; j < 4; j++) {
        const int k = grp * 128 + m * 16 + ((l >> 4) << 2) + j;
        const float dd = aH[m][j] + aM[m][j] * SCL;
        const float dist = fmaf(-2.0f, dd, cbn[k]);
        if (dist < bestd) { bestd = dist; best = k; }
      }
    }
  }

#pragma unroll
  for (int off = 16; off <= 32; off <<= 1) {
    const float d2 = __shfl_xor(bestd, off, 64);
    const int i2 = __shfl_xor(best, off, 64);
    if (d2 < bestd || (d2 == bestd && i2 < best)) { bestd = d2; best = i2; }
  }

#pragma unroll
  for (int i = 0; i < 16; i++) {
    const int d = (l >> 4) * 16 + i;
    zp[(size_t)d * 4096 + pos] = cb[d * 512 + best];
  }
}

// ---------------- conv 4x4 s2 p1 via MFMA fp16x2, LDS-staged weights ------
template<int CIN, int COT, bool RELU_OUT>
__global__ __launch_bounds__(256, 2) void conv4s2_mfma(
    const float* __restrict__ x, const ushort* __restrict__ wpk,
    const float* __restrict__ bias, float* __restrict__ y) {
  constexpr int nCh = CIN / 32, nM = COT / 16;
  constexpr int nStep = nCh * 2;
  constexpr int nTap = nStep * 8;
  __shared__ ushort act[2][2][2][66][40];   // 42,240 B
  __shared__ ushort wlds[2][8192];          // 32,768 B
  const int tid = threadIdx.x;
  const int l = tid & 63;
  const int wv = rfl(tid >> 6);
  const int ho = (blockIdx.x & 7) * 8 + (blockIdx.x >> 3);
  const int n = blockIdx.z;

  {
    uint* lp = (uint*)&act[0][0][0][0][0];
    for (int s = tid; s < 16 * 20; s += 256) {
      const int c = s / 20, w32 = s % 20;
      const int which = c & 1, rest = c >> 1;
      lp[(size_t)(rest * 66 + (which ? 65 : 0)) * 20 + w32] = 0;
    }
  }

  const float* xn = x + ((size_t)n * CIN) * 16384;

  float2 sreg[2][4][2];
  float rmask[2];
  auto LOADG = [&](int step) {
    const int ch = step >> 1, h = step & 1;
#pragma unroll
    for (int rr = 0; rr < 2; rr++) {
      const int ir = 2 * ho - 1 + 2 * h + rr;
      const bool ok = (ir >= 0) && (ir < 128);
      const int irc = ok ? ir : 0;
      rmask[rr] = ok ? 1.0f : 0.0f;
#pragma unroll
      for (int cc = 0; cc < 4; cc++) {
        const int ci0 = ch * 32 + cc * 8 + wv * 2;
        sreg[rr][cc][0] = *(const float2*)(xn + (size_t)ci0 * 16384 + irc * 128 + 2 * l);
        sreg[rr][cc][1] = *(const float2*)(xn + (size_t)(ci0 + 1) * 16384 + irc * 128 + 2 * l);
      }
    }
  };
  auto WRITE = [&]() {
    uint* base = (uint*)&act[0][0][0][0][0];
#pragma unroll
    for (int rr = 0; rr < 2; rr++) {
#pragma unroll
      for (int cc = 0; cc < 4; cc++) {
        const float e0 = sreg[rr][cc][0].x * rmask[rr], o0 = sreg[rr][cc][0].y * rmask[rr];
        const float e1 = sreg[rr][cc][1].x * rmask[rr], o1 = sreg[rr][cc][1].y * rmask[rr];
        const ushort he0 = f2h(e0), ho_0 = f2h(o0);
        const ushort he1 = f2h(e1), ho_1 = f2h(o1);
        const ushort le0 = f2h((e0 - h2f(he0)) * 2048.0f);
        const ushort lo0 = f2h((o0 - h2f(ho_0)) * 2048.0f);
        const ushort le1 = f2h((e1 - h2f(he1)) * 2048.0f);
        const ushort lo1 = f2h((o1 - h2f(ho_1)) * 2048.0f);
        const int u = cc * 4 + wv;
        const size_t sl20 = (size_t)(l + 1) * 20 + u;
        base[(size_t)((0 * 2 + rr) * 2 + 0) * 1320 + sl20] = pk(he0, he1);
        base[(size_t)((0 * 2 + rr) * 2 + 1) * 1320 + sl20] = pk(ho_0, ho_1);
        base[(size_t)((1 * 2 + rr) * 2 + 0) * 1320 + sl20] = pk(le0, le1);
        base[(size_t)((1 * 2 + rr) * 2 + 1) * 1320 + sl20] = pk(lo0, lo1);
      }
    }
  };
  auto STAGEW = [&](int t, int buf) {
    const ushort* src = wpk + (size_t)t * 8192;
    ushort* dst = &wlds[buf][0];
#pragma unroll
    for (int j = 0; j < 4; j++)
      async_copy16((const float*)(src + (j * 256 + tid) * 8),
                   (float*)(dst + (j * 256 + tid) * 8));
  };

  f32x4 accH[nM], accM[nM];
#pragma unroll
  for (int m = 0; m < nM; m++) {
    const int co = m * 16 + ((l >> 4) << 2);
    accH[m] = (f32x4){bias[co], bias[co + 1], bias[co + 2], bias[co + 3]};
    accM[m] = (f32x4){0.f, 0.f, 0.f, 0.f};
  }

  const int pb = wv * 16;
  const int sw = (16 * l) ^ ((l & 4) ? 8 : 0);
  STAGEW(0, 0);
  LOADG(0);
  int tcnt = 0;
  for (int step = 0; step < nStep; step++) {
    __syncthreads();
    WRITE();
    __syncthreads();
#pragma unroll
    for (int rr = 0; rr < 2; rr++) {
#pragma unroll
      for (int kw = 0; kw < 4; kw++) {
        if (!(rr == 0 && kw == 0)) __syncthreads();
        if (tcnt + 1 < nTap) STAGEW(tcnt + 1, (tcnt + 1) & 1);
        if (rr == 0 && kw == 0 && step + 1 < nStep) LOADG(step + 1);
        const ushort* wb = &wlds[tcnt & 1][0];
        const int eo = (kw == 0 || kw == 2) ? 1 : 0;
        const int sh = (kw == 0) ? 0 : (kw == 3) ? 2 : 1;
        const int sl = pb + (l & 15) + sh;
        const h16x8 bh = *(const h16x8*)(&act[0][rr][eo][sl][(l >> 4) * 8]);
        const h16x8 bl = *(const h16x8*)(&act[1][rr][eo][sl][(l >> 4) * 8]);
#pragma unroll
        for (int m = 0; m < nM; m++) {
          const h16x8 ah = *(const h16x8*)(wb + m * 1024 + sw);
          const h16x8 al = *(const h16x8*)(wb + m * 1024 + (sw ^ 8));
          accH[m] = __builtin_amdgcn_mfma_f32_16x16x32_f16(ah, bh, accH[m], 0, 0, 0);
          accM[m] = __builtin_amdgcn_mfma_f32_16x16x32_f16(al, bh, accM[m], 0, 0, 0);
          accM[m] = __builtin_amdgcn_mfma_f32_16x16x32_f16(ah, bl, accM[m], 0, 0, 0);
        }
        tcnt++;
      }
    }
  }

  const float SCL = 1.0f / 2048.0f;
  const int pos = pb + (l & 15);
  const int r4 = (l >> 4) << 2;
#pragma unroll
  for (int m = 0; m < nM; m++) {
    const int co = m * 16 + r4;
    float* yp = y + (((size_t)(n * COT + co)) * 64 + ho) * 64 + pos;
#pragma unroll
    for (int j = 0; j < 4; j++) {
      float v = accH[m][j] + accM[m][j] * SCL;
      if (RELU_OUT) v = fmaxf(v, 0.f);
      yp[(size_t)j * 4096] = v;
    }
  }
}

// ---------------- conv 3x3 s1 p1, MFMA fp16x2, 2 rows/block, COT-tiled ----
// grid = (32, COT/TILE, N). Block = rows r0,r0+1 x TILE outputs.
// Act: 2 planes x 4 rows (shared staging; each weight read feeds 2 B-frags).
// Weight dbuf 2 x nMt KB slices of R29 slabs. acc = 2*nMt*8 VGPRs.
// TILE=64: acc 64 VGPR, LDS 58.6 KB (2 blocks/CU). TILE=32: 46.3 KB.
template<int CIN, int COT, int TILE, bool RELU_IN>
__global__ __launch_bounds__(256, 2) void conv3_mfma2(
    const float* __restrict__ x, const ushort* __restrict__ wpk,
    const float* __restrict__ bias, float* __restrict__ y) {
  constexpr int nCh = CIN / 32, nMf = COT / 16, nMt = TILE / 16;
  constexpr int nTap = nCh * 9;
  __shared__ ushort act[2][4 * 66 * 40];    // 42,240 B
  __shared__ ushort wlds[2][nMt * 1024];    // 2 x nMt*2 KB
  const int tid = threadIdx.x;
  const int l = tid & 63;
  const int wv = rfl(tid >> 6);             // 0..3
  const int r0 = blockIdx.x * 2;            // output rows r0, r0+1
  const int hblk = blockIdx.y;              // co tile
  const int n = blockIdx.z;

  // zero pad slots 0 and 65: 2 planes x 4 rows x 2 slots
  {
    uint* lp = (uint*)&act[0][0];
    for (int s = tid; s < 16 * 20; s += 256) {
      const int c = s / 20, w32 = s % 20;
      const int which = c & 1;
      const int rowrel = (c >> 1) & 3;
      const int plane  = c >> 3;
      lp[(size_t)(plane * 264 + rowrel * 66 + (which ? 65 : 0)) * 20 + w32] = 0;
    }
  }

  const float* xn = x + ((size_t)n * CIN) * 4096;

  float sreg[4][4][2];
  auto LOADG = [&](int ch) {
#pragma unroll
    for (int rr = 0; rr < 4; rr++) {
      const int ir = r0 - 1 + rr;
      const bool ok = (ir >= 0) && (ir < 64);
#pragma unroll
      for (int cc = 0; cc < 4; cc++) {
        const int ci0 = ch * 32 + cc * 8 + wv * 2;
        sreg[rr][cc][0] = ok ? xn[((size_t)ci0 * 64 + ir) * 64 + l] : 0.f;
        sreg[rr][cc][1] = ok ? xn[((size_t)(ci0 + 1) * 64 + ir) * 64 + l] : 0.f;
      }
    }
  };
  auto WRITE = [&]() {
    uint* ph = (uint*)&act[0][0];
    uint* pl = (uint*)&act[1][0];
#pragma unroll
    for (int rr = 0; rr < 4; rr++) {
#pragma unroll
      for (int cc = 0; cc < 4; cc++) {
        float v0 = sreg[rr][cc][0], v1 = sreg[rr][cc][1];
        if (RELU_IN) { v0 = fmaxf(v0, 0.f); v1 = fmaxf(v1, 0.f); }
        const ushort h0 = f2h(v0), h1 = f2h(v1);
        const ushort m0 = f2h((v0 - h2f(h0)) * 2048.0f);
        const ushort m1 = f2h((v1 - h2f(h1)) * 2048.0f);
        const int idx = (rr * 66 + (l + 1)) * 20 + cc * 4 + wv;   // u32 index
        ph[idx] = (uint)h0 | ((uint)h1 << 16);
        pl[idx] = (uint)m0 | ((uint)m1 << 16);
      }
    }
  };
  auto STAGEW = [&](int t, int buf) {
    const ushort* src = wpk + (size_t)t * (nMf * 1024) + hblk * (nMt * 1024);
    ushort* dst = &wlds[buf][0];
#pragma unroll
    for (int j = 0; j < nMt / 2; j++)
      async_copy16((const float*)(src + (j * 256 + tid) * 8),
                   (float*)(dst + (j * 256 + tid) * 8));
  };

  f32x4 accH[2][nMt], accM[2][nMt];
#pragma unroll
  for (int m = 0; m < nMt; m++) {
    const int co = hblk * TILE + m * 16 + ((l >> 4) << 2);
    const f32x4 b4 = (f32x4){bias[co], bias[co + 1], bias[co + 2], bias[co + 3]};
#pragma unroll
    for (int ro = 0; ro < 2; ro++) {
      accH[ro][m] = b4;
      accM[ro][m] = (f32x4){0.f, 0.f, 0.f, 0.f};
    }
  }

  const int pb = wv * 16;
  const int sw = (16 * l) ^ ((l & 4) ? 8 : 0);
  STAGEW(0, 0);
  LOADG(0);
  int tcnt = 0;
  for (int ch = 0; ch < nCh; ch++) {
    __syncthreads();                 // act readers done; DMA + loads drained
    WRITE();                         // act(ch): 4 rows
    __syncthreads();                 // act visible; = tap barrier for tap 0
#pragma unroll
    for (int kh = 0; kh < 3; kh++) {
#pragma unroll
      for (int kw = 0; kw < 3; kw++) {
        if (!(kh == 0 && kw == 0)) __syncthreads();   // tap barrier
        if (tcnt + 1 < nTap) STAGEW(tcnt + 1, (tcnt + 1) & 1);
        if (kh == 0 && kw == 0 && ch + 1 < nCh) LOADG(ch + 1);
        const ushort* wb = &wlds[tcnt & 1][0];
        // B-frags for both output rows (staged row = ro + kh)
        h16x8 bh[2], bl[2];
#pragma unroll
        for (int ro = 0; ro < 2; ro++) {
          const int slot = (ro + kh) * 66 + pb + (l & 15) + kw;
          bh[ro] = *(const h16x8*)(&act[0][0] + slot * 40 + (l >> 4) * 8);
          bl[ro] = *(const h16x8*)(&act[1][0] + slot * 40 + (l >> 4) * 8);
        }
#pragma unroll
        for (int m = 0; m < nMt; m++) {
          const h16x8 ah = *(const h16x8*)(wb + m * 1024 + sw);
          const h16x8 al = *(const h16x8*)(wb + m * 1024 + (sw ^ 8));
#pragma unroll
          for (int ro = 0; ro < 2; ro++) {
            accH[ro][m] = __builtin_amdgcn_mfma_f32_16x16x32_f16(ah, bh[ro], accH[ro][m], 0, 0, 0);
            accM[ro][m] = __builtin_amdgcn_mfma_f32_16x16x32_f16(al, bh[ro], accM[ro][m], 0, 0, 0);
            accM[ro][m] = __builtin_amdgcn_mfma_f32_16x16x32_f16(ah, bl[ro], accM[ro][m], 0, 0, 0);
          }
        }
        tcnt++;
      }
    }
  }

  const float SCL = 1.0f / 2048.0f;
  const int pos = pb + (l & 15);
  const int r4 = (l >> 4) << 2;
#pragma unroll
  for (int ro = 0; ro < 2; ro++) {
#pragma unroll
    for (int m = 0; m < nMt; m++) {
      const int co = hblk * TILE + m * 16 + r4;
      float* yp = y + (((size_t)(n * COT + co)) * 64 + (r0 + ro)) * 64 + pos;
#pragma unroll
      for (int j = 0; j < 4; j++)
        yp[(size_t)j * 4096] = accH[ro][m][j] + accM[ro][m][j] * SCL;
    }
  }
}

// ---------------- ConvTranspose 4x4 s2 p1, MFMA fp16x2, 2 taps/phase ------
template<int CIN, int COT, bool RELU_OUT>
__global__ __launch_bounds__(256, 2) void convt_mfma(
    const float* __restrict__ x, const ushort* __restrict__ wpk,
    const float* __restrict__ bias, float* __restrict__ y) {
  constexpr int nCh = CIN / 32, nM = COT / 16;
  constexpr int nPair = nCh * 8;
  __shared__ ushort act[2][3 * 66 * 40];    // 31,680 B
  __shared__ ushort wlds[2][2 * nM * 1024]; // 2 x 16 KB
  const int tid = threadIdx.x;
  const int l = tid & 63;
  const int wv = rfl(tid >> 6);
  const int a = blockIdx.x;                 // input row 0..63
  const int n = blockIdx.z;

  {
    uint* lp = (uint*)&act[0][0];
    for (int s = tid; s < 12 * 20; s += 256) {
      const int c = s / 20, w32 = s % 20;
      const int which = c & 1;
      const int rowrel = (c >> 1) % 3;
      const int plane  = (c >> 1) / 3;
      lp[(size_t)(plane * 198 + rowrel * 66 + (which ? 65 : 0)) * 20 + w32] = 0;
    }
  }

  const float* xn = x + ((size_t)n * CIN) * 4096;

  float sreg[3][4][2];
  auto LOADG = [&](int ch) {
#pragma unroll
    for (int rr = 0; rr < 3; rr++) {
      const int ir = a - 1 + rr;
      const bool ok = (ir >= 0) && (ir < 64);
#pragma unroll
      for (int cc = 0; cc < 4; cc++) {
        const int ci0 = ch * 32 + cc * 8 + wv * 2;
        sreg[rr][cc][0] = ok ? xn[((size_t)ci0 * 64 + ir) * 64 + l] : 0.f;
        sreg[rr][cc][1] = ok ? xn[((size_t)(ci0 + 1) * 64 + ir) * 64 + l] : 0.f;
      }
    }
  };
  auto WRITE = [&]() {
    uint* ph = (uint*)&act[0][0];
    uint* pl = (uint*)&act[1][0];
#pragma unroll
    for (int rr = 0; rr < 3; rr++) {
#pragma unroll
      for (int cc = 0; cc < 4; cc++) {
        const float v0 = sreg[rr][cc][0], v1 = sreg[rr][cc][1];
        const ushort h0 = f2h(v0), h1 = f2h(v1);
        const ushort m0 = f2h((v0 - h2f(h0)) * 2048.0f);
        const ushort m1 = f2h((v1 - h2f(h1)) * 2048.0f);
        const int idx = (rr * 66 + (l + 1)) * 20 + cc * 4 + wv;
        ph[idx] = (uint)h0 | ((uint)h1 << 16);
        pl[idx] = (uint)m0 | ((uint)m1 << 16);
      }
    }
  };
  auto STAGEW2 = [&](int p, int buf) {
    const ushort* src = wpk + (size_t)p * (2 * nM * 1024);
    ushort* dst = &wlds[buf][0];
#pragma unroll
    for (int j = 0; j < nM; j++)
      async_copy16((const float*)(src + (j * 256 + tid) * 8),
                   (float*)(dst + (j * 256 + tid) * 8));
  };

  f32x4 aH[4][nM], aM[4][nM];
#pragma unroll
  for (int m = 0; m < nM; m++) {
    const int co = m * 16 + ((l >> 4) << 2);
    const f32x4 b4 = (f32x4){bias[co], bias[co + 1], bias[co + 2], bias[co + 3]};
#pragma unroll
    for (int o = 0; o < 4; o++) { aH[o][m] = b4; aM[o][m] = (f32x4){0.f,0.f,0.f,0.f}; }
  }

  const int pb = wv * 16;
  const int sw = (16 * l) ^ ((l & 4) ? 8 : 0);
  STAGEW2(0, 0);
  LOADG(0);
  int pcnt = 0;

#define CT_TAP(WOFS, RR, DD, OIDX) {                                          \
    const int slot = (RR) * 66 + pb + (l & 15) + 1 + (DD);                    \
    const h16x8 bh = *(const h16x8*)(&act[0][0] + slot * 40 + (l >> 4) * 8);  \
    const h16x8 bl = *(const h16x8*)(&act[1][0] + slot * 40 + (l >> 4) * 8);  \
    _Pragma("unroll")                                                         \
    for (int m = 0; m < nM; m++) {                                            \
      const h16x8 ah = *(const h16x8*)(wb + (WOFS) + m * 1024 + sw);          \
      const h16x8 al = *(const h16x8*)(wb + (WOFS) + m * 1024 + (sw ^ 8));    \
      aH[OIDX][m] = __builtin_amdgcn_mfma_f32_16x16x32_f16(ah, bh, aH[OIDX][m], 0, 0, 0); \
      aM[OIDX][m] = __builtin_amdgcn_mfma_f32_16x16x32_f16(al, bh, aM[OIDX][m], 0, 0, 0); \
      aM[OIDX][m] = __builtin_amdgcn_mfma_f32_16x16x32_f16(ah, bl, aM[OIDX][m], 0, 0, 0); \
    }}
#define CT_PHASE(RRA, DDA, OA, RRB, DDB, OB) {                                \
    if (!first) __syncthreads();                                              \
    first = false;                                                            \
    if (pcnt + 1 < nPair) STAGEW2(pcnt + 1, (pcnt + 1) & 1);                  \
    if (doLoad) { if (ch + 1 < nCh) LOADG(ch + 1); doLoad = false; }          \
    const ushort* wb = &wlds[pcnt & 1][0];                                    \
    CT_TAP(0, RRA, DDA, OA)                                                   \
    CT_TAP(nM * 1024, RRB, DDB, OB)                                           \
    pcnt++; }

  for (int ch = 0; ch < nCh; ch++) {
    __syncthreads();                 // prev phase done; DMA + loads drained
    WRITE();                         // act(ch)
    __syncthreads();                 // act visible; = barrier for phase 0
    bool first = true, doLoad = true;
    CT_PHASE(0, -1, 0,  0,  0, 0)
    CT_PHASE(0,  0, 1,  0, +1, 1)
    CT_PHASE(1, -1, 0,  1, -1, 2)
    CT_PHASE(1,  0, 0,  1,  0, 1)
    CT_PHASE(1,  0, 2,  1,  0, 3)
    CT_PHASE(1, +1, 1,  1, +1, 3)
    CT_PHASE(2, -1, 2,  2,  0, 2)
    CT_PHASE(2,  0, 3,  2, +1, 3)
  }
#undef CT_TAP
#undef CT_PHASE

  const float SCL = 1.0f / 2048.0f;
  const int b = pb + (l & 15);
  const int oh0 = 2 * a;
  const int r4 = (l >> 4) << 2;
#pragma unroll
  for (int m = 0; m < nM; m++) {
    const int co = m * 16 + r4;
#pragma unroll
    for (int j = 0; j < 4; j++) {
      float v0e = aH[0][m][j] + aM[0][m][j] * SCL;
      float v0o = aH[1][m][j] + aM[1][m][j] * SCL;
      float v1e = aH[2][m][j] + aM[2][m][j] * SCL;
      float v1o = aH[3][m][j] + aM[3][m][j] * SCL;
      if (RELU_OUT) {
        v0e = fmaxf(v0e, 0.f); v0o = fmaxf(v0o, 0.f);
        v1e = fmaxf(v1e, 0.f); v1o = fmaxf(v1o, 0.f);
      }
      float* row0 = y + (((size_t)(n * COT + co + j)) * 128 + oh0) * 128;
      ((float2*)row0)[b] = make_float2(v0e, v0o);
      ((float2*)(row0 + 128))[b] = make_float2(v1e, v1o);
    }
  }
}

// ---------------- conv 4x4 stride2 pad1 (generic, used for conv0) ---------
template<int CIN, int COT, bool RELU_OUT, int OW>
__global__ __launch_bounds__(256) void conv4s2_row(
    const float* __restrict__ x, const float* __restrict__ w,
    const float* __restrict__ bias, float* __restrict__ y,
    int Hout, int Cout) {
  const int Win = OW * 2, Hin = Hout * 2;
  const int t = blockIdx.x * 256 + threadIdx.x;
  const int wo = t & (OW - 1);
  const int ho = rfl(t / OW);
  const int co0 = blockIdx.y * COT, n = blockIdx.z;

  float acc[COT];
#pragma unroll
  for (int u = 0; u < COT; u++) acc[u] = bias[co0 + u];

  const int iw0 = 2 * wo - 1;
  const int cA = iw0 < 0 ? 0 : iw0;
  const bool mA = iw0 >= 0;
  const int cD = (iw0 + 3 < Win) ? iw0 + 3 : Win - 1;
  const bool mD = iw0 + 3 < Win;

  for (int ci = 0; ci < CIN; ci++) {
    const float* xp = x + ((size_t)(n * CIN + ci)) * Hin * Win;
    const float* wp = w + ((size_t)(co0 * CIN + ci)) * 16;
#pragma unroll
    for (int kh = 0; kh < 4; kh++) {
      const int ih = 2 * ho - 1 + kh;
      if (ih >= 0 && ih < Hin) {
        const float* row = xp + (size_t)ih * Win;
        float x0 = row[cA];      x0 = mA ? x0 : 0.f;
        float x1 = row[iw0 + 1];
        float x2 = row[iw0 + 2];
        float x3 = row[cD];      x3 = mD ? x3 : 0.f;
#pragma unroll
        for (int u = 0; u < COT; u++) {
          const float* wr = wp + u * CIN * 16 + kh * 4;
          acc[u] = fmaf(x0, wr[0], acc[u]);
          acc[u] = fmaf(x1, wr[1], acc[u]);
          acc[u] = fmaf(x2, wr[2], acc[u]);
          acc[u] = fmaf(x3, wr[3], acc[u]);
        }
      }
    }
  }
#pragma unroll
  for (int u = 0; u < COT; u++) {
    float v = acc[u];
    if (RELU_OUT) v = fmaxf(v, 0.f);
    y[(((size_t)(n * Cout + co0 + u)) * Hout + ho) * OW + wo] = v;
  }
}

// ---------------- conv 1x1 v4: 4 positions per thread ---------------------
template<int CIN, int COT, bool RELU_IN, bool ACCUM, bool RELU_OUT>
__global__ __launch_bounds__(256) void conv1x1_v4(
    const float* __restrict__ x, const float* __restrict__ w,
    const float* __restrict__ bias, float* __restrict__ y,
    int HW, int Cout) {
  const int p = (blockIdx.x * 256 + threadIdx.x) * 4;
  const int co0 = blockIdx.y * COT, n = blockIdx.z;

  float4 acc[COT];
#pragma unroll
  for (int u = 0; u < COT; u++) {
    const float b = bias[co0 + u];
    acc[u] = make_float4(b, b, b, b);
  }
  for (int ci = 0; ci < CIN; ci++) {
    float4 xv = *(const float4*)&x[((size_t)(n * CIN + ci)) * HW + p];
    if (RELU_IN) {
      xv.x = fmaxf(xv.x, 0.f); xv.y = fmaxf(xv.y, 0.f);
      xv.z = fmaxf(xv.z, 0.f); xv.w = fmaxf(xv.w, 0.f);
    }
#pragma unroll
    for (int u = 0; u < COT; u++) {
      const float wv = w[(co0 + u) * CIN + ci];
      acc[u].x = fmaf(xv.x, wv, acc[u].x);
      acc[u].y = fmaf(xv.y, wv, acc[u].y);
      acc[u].z = fmaf(xv.z, wv, acc[u].z);
      acc[u].w = fmaf(xv.w, wv, acc[u].w);
    }
  }
#pragma unroll
  for (int u = 0; u < COT; u++) {
    float4* yp = (float4*)&y[((size_t)(n * Cout + co0 + u)) * HW + p];
    float4 r = acc[u];
    if (ACCUM) {
      float4 h = *yp;
      r.x += h.x; r.y += h.y; r.z += h.z; r.w += h.w;
    }
    if (RELU_OUT) {
      r.x = fmaxf(r.x, 0.f); r.y = fmaxf(r.y, 0.f);
      r.z = fmaxf(r.z, 0.f); r.w = fmaxf(r.w, 0.f);
    }
    *yp = r;
  }
}

// ---------------- ConvTranspose 4x4 s2 p1 (generic, used for up1) ---------
template<int CIN, int COT, bool RELU_IN, bool RELU_OUT, int WH>
__global__ __launch_bounds__(256) void convt_row(
    const float* __restrict__ x, const float* __restrict__ w,
    const float* __restrict__ bias, float* __restrict__ y,
    int Hin, int Cout) {
  const int Hout = Hin * 2;
  const int t = blockIdx.x * 256 + threadIdx.x;
  const int a = t & (WH - 1);
  const int oh = rfl(t / WH);
  const int co0 = blockIdx.y * COT, n = blockIdx.z;

  float acc0[COT], acc1[COT];
#pragma unroll
  for (int u = 0; u < COT; u++) { acc0[u] = bias[co0 + u]; acc1[u] = bias[co0 + u]; }

  const int cm = a > 0 ? a - 1 : 0;
  const bool mm = a > 0;
  const int cp = a < WH - 1 ? a + 1 : WH - 1;
  const bool mp = a < WH - 1;

  const int kh0 = (oh + 1) & 1;
#pragma unroll
  for (int dh = 0; dh < 2; dh++) {
    const int kh = kh0 + 2 * dh;
    const int ih = (oh + 1 - kh) >> 1;
    if (ih >= 0 && ih < Hin) {
      for (int ci = 0; ci < CIN; ci++) {
        const float* row = x + (((size_t)(n * CIN + ci)) * Hin + ih) * WH;
        float x0  = row[a];
        float xm1 = row[cm];  xm1 = mm ? xm1 : 0.f;
        float xp1 = row[cp];  xp1 = mp ? xp1 : 0.f;
        if (RELU_IN) {
          x0 = fmaxf(x0, 0.f); xm1 = fmaxf(xm1, 0.f); xp1 = fmaxf(xp1, 0.f);
        }
        const float* wp = w + ((size_t)(ci * Cout + co0)) * 16 + kh * 4;
#pragma unroll
        for (int u = 0; u < COT; u++) {
          const float* wr = wp + u * 16;
          acc0[u] = fmaf(x0,  wr[1], acc0[u]);
          acc0[u] = fmaf(xm1, wr[3], acc0[u]);
          acc1[u] = fmaf(xp1, wr[0], acc1[u]);
          acc1[u] = fmaf(x0,  wr[2], acc1[u]);
        }
      }
    }
  }
#pragma unroll
  for (int u = 0; u < COT; u++) {
    float v0 = acc0[u], v1 = acc1[u];
    if (RELU_OUT) { v0 = fmaxf(v0, 0.f); v1 = fmaxf(v1, 0.f); }
    float* row = y + (((size_t)(n * Cout + co0 + u)) * Hout + oh) * (2 * WH);
    ((float2*)row)[a] = make_float2(v0, v1);
  }
}

// -------------------------------------------------------------------------
extern "C" void kernel_launch(void* const* d_in, const int* in_sizes, int n_in,
                              void* d_out, int out_size, void* d_ws, size_t ws_size,
                              hipStream_t stream) {
  const float* x          = (const float*)d_in[0];
  const float* enc_w0     = (const float*)d_in[1];
  const float* enc_b0     = (const float*)d_in[2];
  const float* enc_w1     = (const float*)d_in[3];
  const float* enc_b1     = (const float*)d_in[4];
  const float* enc_wf     = (const float*)d_in[5];
  const float* enc_bf     = (const float*)d_in[6];
  const float* enc_res_w1 = (const float*)d_in[7];
  const float* enc_res_b1 = (const float*)d_in[8];
  const float* enc_res_w2 = (const float*)d_in[9];
  const float* enc_res_b2 = (const float*)d_in[10];
  const float* pre_w      = (const float*)d_in[11];
  const float* pre_b      = (const float*)d_in[12];
  const float* codebook   = (const float*)d_in[13];
  const float* dec_w      = (const float*)d_in[14];
  const float* dec_b      = (const float*)d_in[15];
  const float* dec_res_w1 = (const float*)d_in[16];
  const float* dec_res_b1 = (const float*)d_in[17];
  const float* dec_res_w2 = (const float*)d_in[18];
  const float* dec_res_b2 = (const float*)d_in[19];
  const float* up_w0      = (const float*)d_in[20];
  const float* up_b0      = (const float*)d_in[21];
  const float* up_w1      = (const float*)d_in[22];
  const float* up_b1      = (const float*)d_in[23];
  float* out = (float*)d_out;

  float* A = (float*)d_ws;         // 16,777,216 floats (64 MB)
  float* B = A + 16777216;         //  8,388,608 floats (32 MB)
  float* C = B + 8388608;          //  8,388,608 floats (32 MB)
  // conv3 weight packs + VQ packs in A's tail (floats 8.39M..). Written
  // after conv1 (A dead then); later A writers stay below 4.2M floats;
  // dead before up0 rewrites A.
  ushort* wpkF  = (ushort*)(A + 8388608);          // convf  294912 ush
  ushort* wpkEa = wpkF  + 294912;                  // enc r1a 73728
  ushort* wpkEb = wpkEa + 73728;                   // enc r1b 73728
  ushort* wpkD  = wpkEb + 73728;                   // dec    147456
  ushort* wpkDa = wpkD  + 147456;                  // dec r1a 73728
  ushort* wpkDb = wpkDa + 73728;                   // dec r1b 73728
  ushort* cbpk  = wpkDb + 73728;                   // vq cb pack 131072 ush
  float*  cbn   = (float*)(cbpk + 131072);         // 512 floats
  // C head: conv1 pack (dead once conv1 ran; convf then overwrites C),
  // later reused for up0 pack (written after pre, C dead then).
  ushort* wpk1  = (ushort*)C;                      // 262144 ush (512 KB)
  ushort* wpkT  = wpk1 + 262144;                   // 262144 ush

  const dim3 blk(256);
  const int N = 16;

  // --- conv1 weight prepack into C head (C untouched until convf) ---
  prep_w4s<64, 128><<<dim3(64), blk, 0, stream>>>(enc_w1, wpk1);

  // --- Encoder ---
  conv4s2_row<3, 16, true, 128><<<dim3(64, 4, N), blk, 0, stream>>>(
      x, enc_w0, enc_b0, A, 128, 64);
  // conv1: MFMA stride-2 implicit GEMM, LDS-staged weights, A -> B
  conv4s2_mfma<64, 128, true><<<dim3(64, 1, N), blk, 0, stream>>>(
      A, wpk1, enc_b1, B);

  // --- prepacks into A's tail (A dead: conv1 consumed it) ---
  prep_w3s<128, 128><<<dim3(72), blk, 0, stream>>>(enc_wf, wpkF);
  prep_w3s<128, 32><<<dim3(18), blk, 0, stream>>>(enc_res_w1, wpkEa);
  prep_w3s<128, 32><<<dim3(18), blk, 0, stream>>>(
      enc_res_w1 + (size_t)32 * 128 * 9, wpkEb);
  prep_w3s<64, 128><<<dim3(36), blk, 0, stream>>>(dec_w, wpkD);
  prep_w3s<128, 32><<<dim3(18), blk, 0, stream>>>(dec_res_w1, wpkDa);
  prep_w3s<128, 32><<<dim3(18), blk, 0, stream>>>(
      dec_res_w1 + (size_t)32 * 128 * 9, wpkDb);
  prep_cb<<<dim3(16), blk, 0, stream>>>(codebook, cbpk);
  cvt_cbn<<<dim3(2), blk, 0, stream>>>(codebook, cbn);

  // convf: MFMA, 2 rows/block, COT-tiled 2x64 (input B already relu'd)
  conv3_mfma2<128, 128, 64, false><<<dim3(32, 2, N), blk, 0, stream>>>(
      B, wpkF, enc_bf, C);
  // enc res stack on C
  conv3_mfma2<128, 32, 32, true><<<dim3(32, 1, N), blk, 0, stream>>>(
      C, wpkEa, enc_res_b1, A);
  conv1x1_v4<32, 8, true, true, false><<<dim3(4, 16, N), blk, 0, stream>>>(
      A, enc_res_w2, enc_res_b2, C, 4096, 128);
  conv3_mfma2<128, 32, 32, true><<<dim3(32, 1, N), blk, 0, stream>>>(
      C, wpkEb, enc_res_b1 + 32, A);
  conv1x1_v4<32, 8, true, true, true><<<dim3(4, 16, N), blk, 0, stream>>>(
      A, enc_res_w2 + (size_t)128 * 32, enc_res_b2 + 128, C, 4096, 128);
  // pre: C already relu'd -> z in A
  conv1x1_v4<128, 8, false, false, false><<<dim3(4, 8, N), blk, 0, stream>>>(
      C, pre_w, pre_b, A, 4096, 64);

  // --- up0 weight prepack into C (C dead after pre) ---
  prep_wts<128, 64><<<dim3(64), blk, 0, stream>>>(up_w0, wpkT);

  // --- VQ (in-place on A) via MFMA ---
  vq_mfma<<<dim3(1024), blk, 0, stream>>>(codebook, cbpk, cbn, A);

  // --- Decoder ---
  conv3_mfma2<64, 128, 64, false><<<dim3(32, 2, N), blk, 0, stream>>>(
      A, wpkD, dec_b, B);
  conv3_mfma2<128, 32, 32, true><<<dim3(32, 1, N), blk, 0, stream>>>(
      B, wpkDa, dec_res_b1, A);
  conv1x1_v4<32, 8, true, true, false><<<dim3(4, 16, N), blk, 0, stream>>>(
      A, dec_res_w2, dec_res_b2, B, 4096, 128);
  conv3_mfma2<128, 32, 32, true><<<dim3(32, 1, N), blk, 0, stream>>>(
      B, wpkDb, dec_res_b1 + 32, A);
  conv1x1_v4<32, 8, true, true, true><<<dim3(4, 16, N), blk, 0, stream>>>(
      A, dec_res_w2 + (size_t)128 * 32, dec_res_b2 + 128, B, 4096, 128);
  // up0: MFMA ConvTranspose, LDS-staged weights, B (relu'd) -> A, ReLU out
  convt_mfma<128, 64, true><<<dim3(64, 1, N), blk, 0, stream>>>(
      B, wpkT, up_b0, A);
  // up1: A -> out(16,3,256,256)
  convt_row<64, 3, false, false, 128><<<dim3(128, 1, N), blk, 0, stream>>>(
      A, up_w1, up_b1, out, 128, 3);
}

// Round 17
// 697.371 us; speedup vs baseline: 1.1329x; 1.0403x over previous
//
#include <hip/hip_runtime.h>
#include <math.h>

// -------------------------------------------------------------------------
// VQ-VAE forward, fp32, round 36 (resubmit; R16 was an infra failure):
// 1x1 convs (res2 x4, pre) moved to MFMA.
//  - R15 = 725 us (best). Top kernels conv1/up0 are at diminishing returns;
//    the five fp32 conv1x1_v4 dispatches (~35 us each = ~175 us) are the
//    largest untouched block. 1x1 conv = pure GEMM; reuse vq_mfma's proven
//    no-LDS structure: strided f32 loads -> fp16x2 B-frags in regs,
//    A-frags streamed from small L2-resident pack (prep_w1), 3*nM MFMAs
//    per K-chunk, bias/ACCUM/ReLU epilogue on the verified C-layout.
//    Memory floor ~8-12 us/dispatch.
//  - Everything else identical to R15 (725 us, absmax 9.77e-4).
// Remaining fp32 VALU: conv0, up1.
// -------------------------------------------------------------------------

#define DEV __device__ __forceinline__

DEV int rfl(int v) { return __builtin_amdgcn_readfirstlane(v); }

DEV void async_copy16(const float* g, float* l) {
  __builtin_amdgcn_global_load_lds(
      (const __attribute__((address_space(1))) void*)g,
      (__attribute__((address_space(3))) void*)l, 16, 0, 0);
}

typedef __attribute__((ext_vector_type(8))) _Float16 h16x8;
typedef __attribute__((ext_vector_type(4))) float f32x4;

DEV ushort f2h(float f) {
  _Float16 h = (_Float16)f;
  return __builtin_bit_cast(ushort, h);
}
DEV float h2f(ushort u) { return (float)__builtin_bit_cast(_Float16, u); }
DEV uint pk(ushort a, ushort b) { return (uint)a | ((uint)b << 16); }

// ---------------- weight prepack for conv3 (LDS-staged) -------------------
// nCh*9 slabs of nM*1024 ush, slab sid = ch*9 + kh*3 + kw (execution order).
template<int CIN, int COT>
__global__ __launch_bounds__(256) void prep_w3s(
    const float* __restrict__ w, ushort* __restrict__ wpk) {
  constexpr int nCh = CIN / 32, nM = COT / 16;
  const int t = blockIdx.x * 256 + threadIdx.x;
  if (t >= 9 * nCh * nM * 64) return;
  const int l = t & 63;
  const int m = (t >> 6) % nM;
  const int sid = t / (64 * nM);
  const int ch = sid / 9, khkw = sid % 9;
  const int co = m * 16 + (l & 15);
  const int k8 = (l >> 4) * 8;
  const int sw = (16 * l) ^ ((l & 4) ? 8 : 0);
  ushort* slab = wpk + (size_t)sid * (nM * 1024) + m * 1024;
#pragma unroll
  for (int i = 0; i < 8; i++) {
    const int ci = ch * 32 + k8 + i;
    const float v = w[((size_t)co * CIN + ci) * 9 + khkw];
    const ushort hi = f2h(v);
    slab[sw + i]       = hi;
    slab[(sw ^ 8) + i] = f2h((v - h2f(hi)) * 2048.0f);
  }
}

// ---------------- weight prepack for conv4s2_mfma (LDS-staged) ------------
template<int CIN, int COT>
__global__ __launch_bounds__(256) void prep_w4s(
    const float* __restrict__ w, ushort* __restrict__ wpk) {
  const int t = blockIdx.x * 256 + threadIdx.x;   // 32*8*64 = 16384
  if (t >= 16384) return;
  const int l = t & 63;
  const int m = (t >> 6) & 7;
  const int sid = t >> 9;
  const int step = sid >> 3, rr = (sid >> 2) & 1, kw = sid & 3;
  const int ch = step >> 1, h = step & 1;
  const int kh = 2 * h + rr;
  const int tap = kh * 4 + kw;
  const int co = m * 16 + (l & 15);
  const int k8 = (l >> 4) * 8;
  const int sw = (16 * l) ^ ((l & 4) ? 8 : 0);
  ushort* slab = wpk + (size_t)sid * 8192 + m * 1024;
#pragma unroll
  for (int i = 0; i < 8; i++) {
    const int ci = ch * 32 + k8 + i;
    const float v = w[((size_t)co * CIN + ci) * 16 + tap];
    const ushort hi = f2h(v);
    slab[sw + i]       = hi;
    slab[(sw ^ 8) + i] = f2h((v - h2f(hi)) * 2048.0f);
  }
}

// ---------------- weight prepack for convt_mfma (LDS-staged) --------------
template<int CIN, int COT>
__global__ __launch_bounds__(256) void prep_wts(
    const float* __restrict__ w, ushort* __restrict__ wpk) {
  constexpr int nCh = CIN / 32, nM = COT / 16;
  const int t = blockIdx.x * 256 + threadIdx.x;
  if (t >= 16 * nCh * nM * 64) return;
  const int l = t & 63;
  const int m = (t >> 6) % nM;
  const int sid = t / (64 * nM);
  const int ch = sid >> 4, idx = sid & 15;
  const int ord[16] = {15, 13, 14, 12, 7, 11, 5, 6, 9, 10, 4, 8, 3, 1, 2, 0};
  const int tap = ord[idx];
  const int kh = tap >> 2, kw = tap & 3;
  const int co = m * 16 + (l & 15);
  const int k8 = (l >> 4) * 8;
  const int sw = (16 * l) ^ ((l & 4) ? 8 : 0);
  ushort* slab = wpk + (size_t)sid * (nM * 1024) + m * 1024;
#pragma unroll
  for (int i = 0; i < 8; i++) {
    const int ci = ch * 32 + k8 + i;
    const float v = w[(((size_t)ci * COT + co) * 4 + kh) * 4 + kw];
    const ushort hi = f2h(v);
    slab[sw + i]       = hi;
    slab[(sw ^ 8) + i] = f2h((v - h2f(hi)) * 2048.0f);
  }
}

// ---------------- weight prepack for conv1x1_mfma (global-resident) -------
// [kc nCh][m nM][lane 64][hi8 | lo8]; co = m*16+(l&15), k = kc*32+(l>>4)*8+i.
template<int CIN, int COT>
__global__ __launch_bounds__(256) void prep_w1(
    const float* __restrict__ w, ushort* __restrict__ wpk) {
  constexpr int nCh = CIN / 32, nM = COT / 16;
  const int t = blockIdx.x * 256 + threadIdx.x;
  if (t >= nCh * nM * 64) return;
  const int l = t & 63;
  const int m = (t >> 6) % nM;
  const int kc = t / (64 * nM);
  const int co = m * 16 + (l & 15);
  const int k8 = (l >> 4) * 8;
  ushort* o = wpk + (size_t)t * 16;
#pragma unroll
  for (int i = 0; i < 8; i++) {
    const int ci = kc * 32 + k8 + i;
    const float v = w[(size_t)co * CIN + ci];
    const ushort hi = f2h(v);
    o[i]     = hi;
    o[8 + i] = f2h((v - h2f(hi)) * 2048.0f);
  }
}

// ---------------- codebook prepack for vq_mfma ----------------------------
__global__ __launch_bounds__(256) void prep_cb(
    const float* __restrict__ cb, ushort* __restrict__ cbpk) {
  const int t = blockIdx.x * 256 + threadIdx.x;   // 4096
  const int l = t & 63;
  const int m = (t >> 6) & 31;
  const int c = t >> 11;
  const int entry = m * 16 + (l & 15);
  ushort* o = cbpk + (size_t)t * 16;
#pragma unroll
  for (int i = 0; i < 8; i++) {
    const int d = c * 32 + (l >> 4) * 8 + i;
    const float v = cb[d * 512 + entry];
    const ushort hi = f2h(v);
    o[i]     = hi;
    o[8 + i] = f2h((v - h2f(hi)) * 2048.0f);
  }
}

// ---------------- codebook norms (fp64 accum -> fp32), once ---------------
__global__ __launch_bounds__(256) void cvt_cbn(
    const float* __restrict__ cb, float* __restrict__ cbn) {
  const int k = blockIdx.x * 256 + threadIdx.x;   // 0..511
  if (k >= 512) return;
  double s = 0.0;
  for (int d = 0; d < 64; d++) {
    const double c = (double)cb[d * 512 + k];
    s = fma(c, c, s);
  }
  cbn[k] = (float)s;
}

// ---------------- VQ via MFMA fp16x2: argmin + in-place quantize ----------
__global__ __launch_bounds__(256) void vq_mfma(
    const float* __restrict__ cb, const ushort* __restrict__ cbpk,
    const float* __restrict__ cbn, float* __restrict__ zq) {
  const int tid = threadIdx.x;
  const int l = tid & 63;
  const int w = rfl(tid >> 6);
  const int n = blockIdx.x >> 6, row = blockIdx.x & 63;
  float* zp = zq + (size_t)n * 262144 + row * 64;   // [d][64rows][64cols]
  const int pos = w * 16 + (l & 15);

  h16x8 zh[2], zl[2];
#pragma unroll
  for (int c = 0; c < 2; c++) {
#pragma unroll
    for (int i = 0; i < 8; i++) {
      const int d = c * 32 + (l >> 4) * 8 + i;
      const float v = zp[(size_t)d * 4096 + pos];
      const _Float16 h = (_Float16)v;
      zh[c][i] = h;
      zl[c][i] = (_Float16)((v - (float)h) * 2048.0f);
    }
  }

  const float SCL = 1.0f / 2048.0f;
  float bestd = 1e30f;
  int best = 0;
  for (int grp = 0; grp < 4; grp++) {
    f32x4 aH[8], aM[8];
#pragma unroll
    for (int m = 0; m < 8; m++) {
      aH[m] = (f32x4){0.f, 0.f, 0.f, 0.f};
      aM[m] = (f32x4){0.f, 0.f, 0.f, 0.f};
    }
#pragma unroll
    for (int c = 0; c < 2; c++) {
#pragma unroll
      for (int m = 0; m < 8; m++) {
        const ushort* ap = cbpk + ((size_t)(c * 32 + grp * 8 + m) * 64 + l) * 16;
        const h16x8 ah = *(const h16x8*)ap;
        const h16x8 al = *(const h16x8*)(ap + 8);
        aH[m] = __builtin_amdgcn_mfma_f32_16x16x32_f16(ah, zh[c], aH[m], 0, 0, 0);
        aM[m] = __builtin_amdgcn_mfma_f32_16x16x32_f16(al, zh[c], aM[m], 0, 0, 0);
        aM[m] = __builtin_amdgcn_mfma_f32_16x16x32_f16(ah, zl[c], aM[m], 0, 0, 0);
      }
    }
#pragma unroll
    for (int m = 0; m < 8; m++) {
#pragma unroll
      for (int j = 0; j < 4; j++) {
        const int k = grp * 128 + m * 16 + ((l >> 4) << 2) + j;
        const float dd = aH[m][j] + aM[m][j] * SCL;
        const float dist = fmaf(-2.0f, dd, cbn[k]);
        if (dist < bestd) { bestd = dist; best = k; }
      }
    }
  }

#pragma unroll
  for (int off = 16; off <= 32; off <<= 1) {
    const float d2 = __shfl_xor(bestd, off, 64);
    const int i2 = __shfl_xor(best, off, 64);
    if (d2 < bestd || (d2 == bestd && i2 < best)) { bestd = d2; best = i2; }
  }

#pragma unroll
  for (int i = 0; i < 16; i++) {
    const int d = (l >> 4) * 16 + i;
    zp[(size_t)d * 4096 + pos] = cb[d * 512 + best];
  }
}

// ---------------- conv 1x1 via MFMA fp16x2 (no LDS, vq_mfma structure) ----
// Block = 64 positions (4 waves x 16). grid (HW/64, 1, N). Per K-chunk:
// strided f32 loads -> zh/zl frags; nM A-frag pairs from L2-resident pack;
// 3*nM MFMAs. Epilogue: bias init + optional ACCUM/ReLU, verified C-layout.
template<int CIN, int COT, bool RELU_IN, bool ACCUM, bool RELU_OUT>
__global__ __launch_bounds__(256) void conv1x1_mfma(
    const float* __restrict__ x, const ushort* __restrict__ wpk,
    const float* __restrict__ bias, float* __restrict__ y, int HW) {
  constexpr int nCh = CIN / 32, nM = COT / 16;
  const int tid = threadIdx.x;
  const int l = tid & 63;
  const int wv = rfl(tid >> 6);
  const int n = blockIdx.z;
  const int p = blockIdx.x * 64 + wv * 16 + (l & 15);

  const float* xp = x + (size_t)n * CIN * HW + p;

  f32x4 accH[nM], accM[nM];
#pragma unroll
  for (int m = 0; m < nM; m++) {
    const int co = m * 16 + ((l >> 4) << 2);
    accH[m] = (f32x4){bias[co], bias[co + 1], bias[co + 2], bias[co + 3]};
    accM[m] = (f32x4){0.f, 0.f, 0.f, 0.f};
  }

#pragma unroll
  for (int kc = 0; kc < nCh; kc++) {
    h16x8 zh, zl;
#pragma unroll
    for (int i = 0; i < 8; i++) {
      const int ci = kc * 32 + (l >> 4) * 8 + i;
      float v = xp[(size_t)ci * HW];
      if (RELU_IN) v = fmaxf(v, 0.f);
      const _Float16 h = (_Float16)v;
      zh[i] = h;
      zl[i] = (_Float16)((v - (float)h) * 2048.0f);
    }
#pragma unroll
    for (int m = 0; m < nM; m++) {
      const ushort* ap = wpk + ((size_t)(kc * nM + m) * 64 + l) * 16;
      const h16x8 ah = *(const h16x8*)ap;
      const h16x8 al = *(const h16x8*)(ap + 8);
      accH[m] = __builtin_amdgcn_mfma_f32_16x16x32_f16(ah, zh, accH[m], 0, 0, 0);
      accM[m] = __builtin_amdgcn_mfma_f32_16x16x32_f16(al, zh, accM[m], 0, 0, 0);
      accM[m] = __builtin_amdgcn_mfma_f32_16x16x32_f16(ah, zl, accM[m], 0, 0, 0);
    }
  }

  const float SCL = 1.0f / 2048.0f;
#pragma unroll
  for (int m = 0; m < nM; m++) {
    const int co = m * 16 + ((l >> 4) << 2);
    float* yp = y + ((size_t)n * COT + co) * HW + p;
#pragma unroll
    for (int j = 0; j < 4; j++) {
      float r = accH[m][j] + accM[m][j] * SCL;
      if (ACCUM) r += yp[(size_t)j * HW];
      if (RELU_OUT) r = fmaxf(r, 0.f);
      yp[(size_t)j * HW] = r;
    }
  }
}

// ---------------- conv 4x4 s2 p1 via MFMA fp16x2, LDS-staged weights ------
template<int CIN, int COT, bool RELU_OUT>
__global__ __launch_bounds__(256, 2) void conv4s2_mfma(
    const float* __restrict__ x, const ushort* __restrict__ wpk,
    const float* __restrict__ bias, float* __restrict__ y) {
  constexpr int nCh = CIN / 32, nM = COT / 16;
  constexpr int nStep = nCh * 2;
  constexpr int nTap = nStep * 8;
  __shared__ ushort act[2][2][2][66][40];   // 42,240 B
  __shared__ ushort wlds[2][8192];          // 32,768 B
  const int tid = threadIdx.x;
  const int l = tid & 63;
  const int wv = rfl(tid >> 6);
  const int ho = (blockIdx.x & 7) * 8 + (blockIdx.x >> 3);
  const int n = blockIdx.z;

  {
    uint* lp = (uint*)&act[0][0][0][0][0];
    for (int s = tid; s < 16 * 20; s += 256) {
      const int c = s / 20, w32 = s % 20;
      const int which = c & 1, rest = c >> 1;
      lp[(size_t)(rest * 66 + (which ? 65 : 0)) * 20 + w32] = 0;
    }
  }

  const float* xn = x + ((size_t)n * CIN) * 16384;

  float2 sreg[2][4][2];
  float rmask[2];
  auto LOADG = [&](int step) {
    const int ch = step >> 1, h = step & 1;
#pragma unroll
    for (int rr = 0; rr < 2; rr++) {
      const int ir = 2 * ho - 1 + 2 * h + rr;
      const bool ok = (ir >= 0) && (ir < 128);
      const int irc = ok ? ir : 0;
      rmask[rr] = ok ? 1.0f : 0.0f;
#pragma unroll
      for (int cc = 0; cc < 4; cc++) {
        const int ci0 = ch * 32 + cc * 8 + wv * 2;
        sreg[rr][cc][0] = *(const float2*)(xn + (size_t)ci0 * 16384 + irc * 128 + 2 * l);
        sreg[rr][cc][1] = *(const float2*)(xn + (size_t)(ci0 + 1) * 16384 + irc * 128 + 2 * l);
      }
    }
  };
  auto WRITE = [&]() {
    uint* base = (uint*)&act[0][0][0][0][0];
#pragma unroll
    for (int rr = 0; rr < 2; rr++) {
#pragma unroll
      for (int cc = 0; cc < 4; cc++) {
        const float e0 = sreg[rr][cc][0].x * rmask[rr], o0 = sreg[rr][cc][0].y * rmask[rr];
        const float e1 = sreg[rr][cc][1].x * rmask[rr], o1 = sreg[rr][cc][1].y * rmask[rr];
        const ushort he0 = f2h(e0), ho_0 = f2h(o0);
        const ushort he1 = f2h(e1), ho_1 = f2h(o1);
        const ushort le0 = f2h((e0 - h2f(he0)) * 2048.0f);
        const ushort lo0 = f2h((o0 - h2f(ho_0)) * 2048.0f);
        const ushort le1 = f2h((e1 - h2f(he1)) * 2048.0f);
        const ushort lo1 = f2h((o1 - h2f(ho_1)) * 2048.0f);
        const int u = cc * 4 + wv;
        const size_t sl20 = (size_t)(l + 1) * 20 + u;
        base[(size_t)((0 * 2 + rr) * 2 + 0) * 1320 + sl20] = pk(he0, he1);
        base[(size_t)((0 * 2 + rr) * 2 + 1) * 1320 + sl20] = pk(ho_0, ho_1);
        base[(size_t)((1 * 2 + rr) * 2 + 0) * 1320 + sl20] = pk(le0, le1);
        base[(size_t)((1 * 2 + rr) * 2 + 1) * 1320 + sl20] = pk(lo0, lo1);
      }
    }
  };
  auto STAGEW = [&](int t, int buf) {
    const ushort* src = wpk + (size_t)t * 8192;
    ushort* dst = &wlds[buf][0];
#pragma unroll
    for (int j = 0; j < 4; j++)
      async_copy16((const float*)(src + (j * 256 + tid) * 8),
                   (float*)(dst + (j * 256 + tid) * 8));
  };

  f32x4 accH[nM], accM[nM];
#pragma unroll
  for (int m = 0; m < nM; m++) {
    const int co = m * 16 + ((l >> 4) << 2);
    accH[m] = (f32x4){bias[co], bias[co + 1], bias[co + 2], bias[co + 3]};
    accM[m] = (f32x4){0.f, 0.f, 0.f, 0.f};
  }

  const int pb = wv * 16;
  const int sw = (16 * l) ^ ((l & 4) ? 8 : 0);
  STAGEW(0, 0);
  LOADG(0);
  int tcnt = 0;
  for (int step = 0; step < nStep; step++) {
    __syncthreads();
    WRITE();
    __syncthreads();
#pragma unroll
    for (int rr = 0; rr < 2; rr++) {
#pragma unroll
      for (int kw = 0; kw < 4; kw++) {
        if (!(rr == 0 && kw == 0)) __syncthreads();
        if (tcnt + 1 < nTap) STAGEW(tcnt + 1, (tcnt + 1) & 1);
        if (rr == 0 && kw == 0 && step + 1 < nStep) LOADG(step + 1);
        const ushort* wb = &wlds[tcnt & 1][0];
        const int eo = (kw == 0 || kw == 2) ? 1 : 0;
        const int sh = (kw == 0) ? 0 : (kw == 3) ? 2 : 1;
        const int sl = pb + (l & 15) + sh;
        const h16x8 bh = *(const h16x8*)(&act[0][rr][eo][sl][(l >> 4) * 8]);
        const h16x8 bl = *(const h16x8*)(&act[1][rr][eo][sl][(l >> 4) * 8]);
#pragma unroll
        for (int m = 0; m < nM; m++) {
          const h16x8 ah = *(const h16x8*)(wb + m * 1024 + sw);
          const h16x8 al = *(const h16x8*)(wb + m * 1024 + (sw ^ 8));
          accH[m] = __builtin_amdgcn_mfma_f32_16x16x32_f16(ah, bh, accH[m], 0, 0, 0);
          accM[m] = __builtin_amdgcn_mfma_f32_16x16x32_f16(al, bh, accM[m], 0, 0, 0);
          accM[m] = __builtin_amdgcn_mfma_f32_16x16x32_f16(ah, bl, accM[m], 0, 0, 0);
        }
        tcnt++;
      }
    }
  }

  const float SCL = 1.0f / 2048.0f;
  const int pos = pb + (l & 15);
  const int r4 = (l >> 4) << 2;
#pragma unroll
  for (int m = 0; m < nM; m++) {
    const int co = m * 16 + r4;
    float* yp = y + (((size_t)(n * COT + co)) * 64 + ho) * 64 + pos;
#pragma unroll
    for (int j = 0; j < 4; j++) {
      float v = accH[m][j] + accM[m][j] * SCL;
      if (RELU_OUT) v = fmaxf(v, 0.f);
      yp[(size_t)j * 4096] = v;
    }
  }
}

// ---------------- conv 3x3 s1 p1, MFMA fp16x2, 2 rows/block, COT-tiled ----
template<int CIN, int COT, int TILE, bool RELU_IN>
__global__ __launch_bounds__(256, 2) void conv3_mfma2(
    const float* __restrict__ x, const ushort* __restrict__ wpk,
    const float* __restrict__ bias, float* __restrict__ y) {
  constexpr int nCh = CIN / 32, nMf = COT / 16, nMt = TILE / 16;
  constexpr int nTap = nCh * 9;
  __shared__ ushort act[2][4 * 66 * 40];    // 42,240 B
  __shared__ ushort wlds[2][nMt * 1024];    // 2 x nMt*2 KB
  const int tid = threadIdx.x;
  const int l = tid & 63;
  const int wv = rfl(tid >> 6);             // 0..3
  const int r0 = blockIdx.x * 2;            // output rows r0, r0+1
  const int hblk = blockIdx.y;              // co tile
  const int n = blockIdx.z;

  {
    uint* lp = (uint*)&act[0][0];
    for (int s = tid; s < 16 * 20; s += 256) {
      const int c = s / 20, w32 = s % 20;
      const int which = c & 1;
      const int rowrel = (c >> 1) & 3;
      const int plane  = c >> 3;
      lp[(size_t)(plane * 264 + rowrel * 66 + (which ? 65 : 0)) * 20 + w32] = 0;
    }
  }

  const float* xn = x + ((size_t)n * CIN) * 4096;

  float sreg[4][4][2];
  auto LOADG = [&](int ch) {
#pragma unroll
    for (int rr = 0; rr < 4; rr++) {
      const int ir = r0 - 1 + rr;
      const bool ok = (ir >= 0) && (ir < 64);
#pragma unroll
      for (int cc = 0; cc < 4; cc++) {
        const int ci0 = ch * 32 + cc * 8 + wv * 2;
        sreg[rr][cc][0] = ok ? xn[((size_t)ci0 * 64 + ir) * 64 + l] : 0.f;
        sreg[rr][cc][1] = ok ? xn[((size_t)(ci0 + 1) * 64 + ir) * 64 + l] : 0.f;
      }
    }
  };
  auto WRITE = [&]() {
    uint* ph = (uint*)&act[0][0];
    uint* pl = (uint*)&act[1][0];
#pragma unroll
    for (int rr = 0; rr < 4; rr++) {
#pragma unroll
      for (int cc = 0; cc < 4; cc++) {
        float v0 = sreg[rr][cc][0], v1 = sreg[rr][cc][1];
        if (RELU_IN) { v0 = fmaxf(v0, 0.f); v1 = fmaxf(v1, 0.f); }
        const ushort h0 = f2h(v0), h1 = f2h(v1);
        const ushort m0 = f2h((v0 - h2f(h0)) * 2048.0f);
        const ushort m1 = f2h((v1 - h2f(h1)) * 2048.0f);
        const int idx = (rr * 66 + (l + 1)) * 20 + cc * 4 + wv;   // u32 index
        ph[idx] = (uint)h0 | ((uint)h1 << 16);
        pl[idx] = (uint)m0 | ((uint)m1 << 16);
      }
    }
  };
  auto STAGEW = [&](int t, int buf) {
    const ushort* src = wpk + (size_t)t * (nMf * 1024) + hblk * (nMt * 1024);
    ushort* dst = &wlds[buf][0];
#pragma unroll
    for (int j = 0; j < nMt / 2; j++)
      async_copy16((const float*)(src + (j * 256 + tid) * 8),
                   (float*)(dst + (j * 256 + tid) * 8));
  };

  f32x4 accH[2][nMt], accM[2][nMt];
#pragma unroll
  for (int m = 0; m < nMt; m++) {
    const int co = hblk * TILE + m * 16 + ((l >> 4) << 2);
    const f32x4 b4 = (f32x4){bias[co], bias[co + 1], bias[co + 2], bias[co + 3]};
#pragma unroll
    for (int ro = 0; ro < 2; ro++) {
      accH[ro][m] = b4;
      accM[ro][m] = (f32x4){0.f, 0.f, 0.f, 0.f};
    }
  }

  const int pb = wv * 16;
  const int sw = (16 * l) ^ ((l & 4) ? 8 : 0);
  STAGEW(0, 0);
  LOADG(0);
  int tcnt = 0;
  for (int ch = 0; ch < nCh; ch++) {
    __syncthreads();                 // act readers done; DMA + loads drained
    WRITE();                         // act(ch): 4 rows
    __syncthreads();                 // act visible; = tap barrier for tap 0
#pragma unroll
    for (int kh = 0; kh < 3; kh++) {
#pragma unroll
      for (int kw = 0; kw < 3; kw++) {
        if (!(kh == 0 && kw == 0)) __syncthreads();   // tap barrier
        if (tcnt + 1 < nTap) STAGEW(tcnt + 1, (tcnt + 1) & 1);
        if (kh == 0 && kw == 0 && ch + 1 < nCh) LOADG(ch + 1);
        const ushort* wb = &wlds[tcnt & 1][0];
        h16x8 bh[2], bl[2];
#pragma unroll
        for (int ro = 0; ro < 2; ro++) {
          const int slot = (ro + kh) * 66 + pb + (l & 15) + kw;
          bh[ro] = *(const h16x8*)(&act[0][0] + slot * 40 + (l >> 4) * 8);
          bl[ro] = *(const h16x8*)(&act[1][0] + slot * 40 + (l >> 4) * 8);
        }
#pragma unroll
        for (int m = 0; m < nMt; m++) {
          const h16x8 ah = *(const h16x8*)(wb + m * 1024 + sw);
          const h16x8 al = *(const h16x8*)(wb + m * 1024 + (sw ^ 8));
#pragma unroll
          for (int ro = 0; ro < 2; ro++) {
            accH[ro][m] = __builtin_amdgcn_mfma_f32_16x16x32_f16(ah, bh[ro], accH[ro][m], 0, 0, 0);
            accM[ro][m] = __builtin_amdgcn_mfma_f32_16x16x32_f16(al, bh[ro], accM[ro][m], 0, 0, 0);
            accM[ro][m] = __builtin_amdgcn_mfma_f32_16x16x32_f16(ah, bl[ro], accM[ro][m], 0, 0, 0);
          }
        }
        tcnt++;
      }
    }
  }

  const float SCL = 1.0f / 2048.0f;
  const int pos = pb + (l & 15);
  const int r4 = (l >> 4) << 2;
#pragma unroll
  for (int ro = 0; ro < 2; ro++) {
#pragma unroll
    for (int m = 0; m < nMt; m++) {
      const int co = hblk * TILE + m * 16 + r4;
      float* yp = y + (((size_t)(n * COT + co)) * 64 + (r0 + ro)) * 64 + pos;
#pragma unroll
      for (int j = 0; j < 4; j++)
        yp[(size_t)j * 4096] = accH[ro][m][j] + accM[ro][m][j] * SCL;
    }
  }
}

// ---------------- ConvTranspose 4x4 s2 p1, MFMA fp16x2, 2 taps/phase ------
template<int CIN, int COT, bool RELU_OUT>
__global__ __launch_bounds__(256, 2) void convt_mfma(
    const float* __restrict__ x, const ushort* __restrict__ wpk,
    const float* __restrict__ bias, float* __restrict__ y) {
  constexpr int nCh = CIN / 32, nM = COT / 16;
  constexpr int nPair = nCh * 8;
  __shared__ ushort act[2][3 * 66 * 40];    // 31,680 B
  __shared__ ushort wlds[2][2 * nM * 1024]; // 2 x 16 KB
  const int tid = threadIdx.x;
  const int l = tid & 63;
  const int wv = rfl(tid >> 6);
  const int a = blockIdx.x;                 // input row 0..63
  const int n = blockIdx.z;

  {
    uint* lp = (uint*)&act[0][0];
    for (int s = tid; s < 12 * 20; s += 256) {
      const int c = s / 20, w32 = s % 20;
      const int which = c & 1;
      const int rowrel = (c >> 1) % 3;
      const int plane  = (c >> 1) / 3;
      lp[(size_t)(plane * 198 + rowrel * 66 + (which ? 65 : 0)) * 20 + w32] = 0;
    }
  }

  const float* xn = x + ((size_t)n * CIN) * 4096;

  float sreg[3][4][2];
  auto LOADG = [&](int ch) {
#pragma unroll
    for (int rr = 0; rr < 3; rr++) {
      const int ir = a - 1 + rr;
      const bool ok = (ir >= 0) && (ir < 64);
#pragma unroll
      for (int cc = 0; cc < 4; cc++) {
        const int ci0 = ch * 32 + cc * 8 + wv * 2;
        sreg[rr][cc][0] = ok ? xn[((size_t)ci0 * 64 + ir) * 64 + l] : 0.f;
        sreg[rr][cc][1] = ok ? xn[((size_t)(ci0 + 1) * 64 + ir) * 64 + l] : 0.f;
      }
    }
  };
  auto WRITE = [&]() {
    uint* ph = (uint*)&act[0][0];
    uint* pl = (uint*)&act[1][0];
#pragma unroll
    for (int rr = 0; rr < 3; rr++) {
#pragma unroll
      for (int cc = 0; cc < 4; cc++) {
        const float v0 = sreg[rr][cc][0], v1 = sreg[rr][cc][1];
        const ushort h0 = f2h(v0), h1 = f2h(v1);
        const ushort m0 = f2h((v0 - h2f(h0)) * 2048.0f);
        const ushort m1 = f2h((v1 - h2f(h1)) * 2048.0f);
        const int idx = (rr * 66 + (l + 1)) * 20 + cc * 4 + wv;
        ph[idx] = (uint)h0 | ((uint)h1 << 16);
        pl[idx] = (uint)m0 | ((uint)m1 << 16);
      }
    }
  };
  auto STAGEW2 = [&](int p, int buf) {
    const ushort* src = wpk + (size_t)p * (2 * nM * 1024);
    ushort* dst = &wlds[buf][0];
#pragma unroll
    for (int j = 0; j < nM; j++)
      async_copy16((const float*)(src + (j * 256 + tid) * 8),
                   (float*)(dst + (j * 256 + tid) * 8));
  };

  f32x4 aH[4][nM], aM[4][nM];
#pragma unroll
  for (int m = 0; m < nM; m++) {
    const int co = m * 16 + ((l >> 4) << 2);
    const f32x4 b4 = (f32x4){bias[co], bias[co + 1], bias[co + 2], bias[co + 3]};
#pragma unroll
    for (int o = 0; o < 4; o++) { aH[o][m] = b4; aM[o][m] = (f32x4){0.f,0.f,0.f,0.f}; }
  }

  const int pb = wv * 16;
  const int sw = (16 * l) ^ ((l & 4) ? 8 : 0);
  STAGEW2(0, 0);
  LOADG(0);
  int pcnt = 0;

#define CT_TAP(WOFS, RR, DD, OIDX) {                                          \
    const int slot = (RR) * 66 + pb + (l & 15) + 1 + (DD);                    \
    const h16x8 bh = *(const h16x8*)(&act[0][0] + slot * 40 + (l >> 4) * 8);  \
    const h16x8 bl = *(const h16x8*)(&act[1][0] + slot * 40 + (l >> 4) * 8);  \
    _Pragma("unroll")                                                         \
    for (int m = 0; m < nM; m++) {                                            \
      const h16x8 ah = *(const h16x8*)(wb + (WOFS) + m * 1024 + sw);          \
      const h16x8 al = *(const h16x8*)(wb + (WOFS) + m * 1024 + (sw ^ 8));    \
      aH[OIDX][m] = __builtin_amdgcn_mfma_f32_16x16x32_f16(ah, bh, aH[OIDX][m], 0, 0, 0); \
      aM[OIDX][m] = __builtin_amdgcn_mfma_f32_16x16x32_f16(al, bh, aM[OIDX][m], 0, 0, 0); \
      aM[OIDX][m] = __builtin_amdgcn_mfma_f32_16x16x32_f16(ah, bl, aM[OIDX][m], 0, 0, 0); \
    }}
#define CT_PHASE(RRA, DDA, OA, RRB, DDB, OB) {                                \
    if (!first) __syncthreads();                                              \
    first = false;                                                            \
    if (pcnt + 1 < nPair) STAGEW2(pcnt + 1, (pcnt + 1) & 1);                  \
    if (doLoad) { if (ch + 1 < nCh) LOADG(ch + 1); doLoad = false; }          \
    const ushort* wb = &wlds[pcnt & 1][0];                                    \
    CT_TAP(0, RRA, DDA, OA)                                                   \
    CT_TAP(nM * 1024, RRB, DDB, OB)                                           \
    pcnt++; }

  for (int ch = 0; ch < nCh; ch++) {
    __syncthreads();                 // prev phase done; DMA + loads drained
    WRITE();                         // act(ch)
    __syncthreads();                 // act visible; = barrier for phase 0
    bool first = true, doLoad = true;
    CT_PHASE(0, -1, 0,  0,  0, 0)
    CT_PHASE(0,  0, 1,  0, +1, 1)
    CT_PHASE(1, -1, 0,  1, -1, 2)
    CT_PHASE(1,  0, 0,  1,  0, 1)
    CT_PHASE(1,  0, 2,  1,  0, 3)
    CT_PHASE(1, +1, 1,  1, +1, 3)
    CT_PHASE(2, -1, 2,  2,  0, 2)
    CT_PHASE(2,  0, 3,  2, +1, 3)
  }
#undef CT_TAP
#undef CT_PHASE

  const float SCL = 1.0f / 2048.0f;
  const int b = pb + (l & 15);
  const int oh0 = 2 * a;
  const int r4 = (l >> 4) << 2;
#pragma unroll
  for (int m = 0; m < nM; m++) {
    const int co = m * 16 + r4;
#pragma unroll
    for (int j = 0; j < 4; j++) {
      float v0e = aH[0][m][j] + aM[0][m][j] * SCL;
      float v0o = aH[1][m][j] + aM[1][m][j] * SCL;
      float v1e = aH[2][m][j] + aM[2][m][j] * SCL;
      float v1o = aH[3][m][j] + aM[3][m][j] * SCL;
      if (RELU_OUT) {
        v0e = fmaxf(v0e, 0.f); v0o = fmaxf(v0o, 0.f);
        v1e = fmaxf(v1e, 0.f); v1o = fmaxf(v1o, 0.f);
      }
      float* row0 = y + (((size_t)(n * COT + co + j)) * 128 + oh0) * 128;
      ((float2*)row0)[b] = make_float2(v0e, v0o);
      ((float2*)(row0 + 128))[b] = make_float2(v1e, v1o);
    }
  }
}

// ---------------- conv 4x4 stride2 pad1 (generic, used for conv0) ---------
template<int CIN, int COT, bool RELU_OUT, int OW>
__global__ __launch_bounds__(256) void conv4s2_row(
    const float* __restrict__ x, const float* __restrict__ w,
    const float* __restrict__ bias, float* __restrict__ y,
    int Hout, int Cout) {
  const int Win = OW * 2, Hin = Hout * 2;
  const int t = blockIdx.x * 256 + threadIdx.x;
  const int wo = t & (OW - 1);
  const int ho = rfl(t / OW);
  const int co0 = blockIdx.y * COT, n = blockIdx.z;

  float acc[COT];
#pragma unroll
  for (int u = 0; u < COT; u++) acc[u] = bias[co0 + u];

  const int iw0 = 2 * wo - 1;
  const int cA = iw0 < 0 ? 0 : iw0;
  const bool mA = iw0 >= 0;
  const int cD = (iw0 + 3 < Win) ? iw0 + 3 : Win - 1;
  const bool mD = iw0 + 3 < Win;

  for (int ci = 0; ci < CIN; ci++) {
    const float* xp = x + ((size_t)(n * CIN + ci)) * Hin * Win;
    const float* wp = w + ((size_t)(co0 * CIN + ci)) * 16;
#pragma unroll
    for (int kh = 0; kh < 4; kh++) {
      const int ih = 2 * ho - 1 + kh;
      if (ih >= 0 && ih < Hin) {
        const float* row = xp + (size_t)ih * Win;
        float x0 = row[cA];      x0 = mA ? x0 : 0.f;
        float x1 = row[iw0 + 1];
        float x2 = row[iw0 + 2];
        float x3 = row[cD];      x3 = mD ? x3 : 0.f;
#pragma unroll
        for (int u = 0; u < COT; u++) {
          const float* wr = wp + u * CIN * 16 + kh * 4;
          acc[u] = fmaf(x0, wr[0], acc[u]);
          acc[u] = fmaf(x1, wr[1], acc[u]);
          acc[u] = fmaf(x2, wr[2], acc[u]);
          acc[u] = fmaf(x3, wr[3], acc[u]);
        }
      }
    }
  }
#pragma unroll
  for (int u = 0; u < COT; u++) {
    float v = acc[u];
    if (RELU_OUT) v = fmaxf(v, 0.f);
    y[(((size_t)(n * Cout + co0 + u)) * Hout + ho) * OW + wo] = v;
  }
}

// ---------------- ConvTranspose 4x4 s2 p1 (generic, used for up1) ---------
template<int CIN, int COT, bool RELU_IN, bool RELU_OUT, int WH>
__global__ __launch_bounds__(256) void convt_row(
    const float* __restrict__ x, const float* __restrict__ w,
    const float* __restrict__ bias, float* __restrict__ y,
    int Hin, int Cout) {
  const int Hout = Hin * 2;
  const int t = blockIdx.x * 256 + threadIdx.x;
  const int a = t & (WH - 1);
  const int oh = rfl(t / WH);
  const int co0 = blockIdx.y * COT, n = blockIdx.z;

  float acc0[COT], acc1[COT];
#pragma unroll
  for (int u = 0; u < COT; u++) { acc0[u] = bias[co0 + u]; acc1[u] = bias[co0 + u]; }

  const int cm = a > 0 ? a - 1 : 0;
  const bool mm = a > 0;
  const int cp = a < WH - 1 ? a + 1 : WH - 1;
  const bool mp = a < WH - 1;

  const int kh0 = (oh + 1) & 1;
#pragma unroll
  for (int dh = 0; dh < 2; dh++) {
    const int kh = kh0 + 2 * dh;
    const int ih = (oh + 1 - kh) >> 1;
    if (ih >= 0 && ih < Hin) {
      for (int ci = 0; ci < CIN; ci++) {
        const float* row = x + (((size_t)(n * CIN + ci)) * Hin + ih) * WH;
        float x0  = row[a];
        float xm1 = row[cm];  xm1 = mm ? xm1 : 0.f;
        float xp1 = row[cp];  xp1 = mp ? xp1 : 0.f;
        if (RELU_IN) {
          x0 = fmaxf(x0, 0.f); xm1 = fmaxf(xm1, 0.f); xp1 = fmaxf(xp1, 0.f);
        }
        const float* wp = w + ((size_t)(ci * Cout + co0)) * 16 + kh * 4;
#pragma unroll
        for (int u = 0; u < COT; u++) {
          const float* wr = wp + u * 16;
          acc0[u] = fmaf(x0,  wr[1], acc0[u]);
          acc0[u] = fmaf(xm1, wr[3], acc0[u]);
          acc1[u] = fmaf(xp1, wr[0], acc1[u]);
          acc1[u] = fmaf(x0,  wr[2], acc1[u]);
        }
      }
    }
  }
#pragma unroll
  for (int u = 0; u < COT; u++) {
    float v0 = acc0[u], v1 = acc1[u];
    if (RELU_OUT) { v0 = fmaxf(v0, 0.f); v1 = fmaxf(v1, 0.f); }
    float* row = y + (((size_t)(n * Cout + co0 + u)) * Hout + oh) * (2 * WH);
    ((float2*)row)[a] = make_float2(v0, v1);
  }
}

// -------------------------------------------------------------------------
extern "C" void kernel_launch(void* const* d_in, const int* in_sizes, int n_in,
                              void* d_out, int out_size, void* d_ws, size_t ws_size,
                              hipStream_t stream) {
  const float* x          = (const float*)d_in[0];
  const float* enc_w0     = (const float*)d_in[1];
  const float* enc_b0     = (const float*)d_in[2];
  const float* enc_w1     = (const float*)d_in[3];
  const float* enc_b1     = (const float*)d_in[4];
  const float* enc_wf     = (const float*)d_in[5];
  const float* enc_bf     = (const float*)d_in[6];
  const float* enc_res_w1 = (const float*)d_in[7];
  const float* enc_res_b1 = (const float*)d_in[8];
  const float* enc_res_w2 = (const float*)d_in[9];
  const float* enc_res_b2 = (const float*)d_in[10];
  const float* pre_w      = (const float*)d_in[11];
  const float* pre_b      = (const float*)d_in[12];
  const float* codebook   = (const float*)d_in[13];
  const float* dec_w      = (const float*)d_in[14];
  const float* dec_b      = (const float*)d_in[15];
  const float* dec_res_w1 = (const float*)d_in[16];
  const float* dec_res_b1 = (const float*)d_in[17];
  const float* dec_res_w2 = (const float*)d_in[18];
  const float* dec_res_b2 = (const float*)d_in[19];
  const float* up_w0      = (const float*)d_in[20];
  const float* up_b0      = (const float*)d_in[21];
  const float* up_w1      = (const float*)d_in[22];
  const float* up_b1      = (const float*)d_in[23];
  float* out = (float*)d_out;

  float* A = (float*)d_ws;         // 16,777,216 floats (64 MB)
  float* B = A + 16777216;         //  8,388,608 floats (32 MB)
  float* C = B + 8388608;          //  8,388,608 floats (32 MB)
  // Packs in A's tail (floats 8.39M..). Written after conv1 (A dead then);
  // later A writers stay below 4.2M floats; all read before up0 rewrites A.
  ushort* wpkF  = (ushort*)(A + 8388608);          // convf  294912 ush
  ushort* wpkEa = wpkF  + 294912;                  // enc r1a 73728
  ushort* wpkEb = wpkEa + 73728;                   // enc r1b 73728
  ushort* wpkD  = wpkEb + 73728;                   // dec    147456
  ushort* wpkDa = wpkD  + 147456;                  // dec r1a 73728
  ushort* wpkDb = wpkDa + 73728;                   // dec r1b 73728
  ushort* cbpk  = wpkDb + 73728;                   // vq cb pack 131072 ush
  float*  cbn   = (float*)(cbpk + 131072);         // 512 floats
  ushort* wpkR2Ea = cbpk + 131072 + 1024;          // enc res2 a  8192 ush
  ushort* wpkR2Eb = wpkR2Ea + 8192;                // enc res2 b  8192
  ushort* wpkR2Da = wpkR2Eb + 8192;                // dec res2 a  8192
  ushort* wpkR2Db = wpkR2Da + 8192;                // dec res2 b  8192
  ushort* wpkP    = wpkR2Db + 8192;                // pre        16384
  // C head: conv1 pack (dead once conv1 ran; convf then overwrites C),
  // later reused for up0 pack (written after pre, C dead then).
  ushort* wpk1  = (ushort*)C;                      // 262144 ush (512 KB)
  ushort* wpkT  = wpk1 + 262144;                   // 262144 ush

  const dim3 blk(256);
  const int N = 16;

  // --- conv1 weight prepack into C head (C untouched until convf) ---
  prep_w4s<64, 128><<<dim3(64), blk, 0, stream>>>(enc_w1, wpk1);

  // --- Encoder ---
  conv4s2_row<3, 16, true, 128><<<dim3(64, 4, N), blk, 0, stream>>>(
      x, enc_w0, enc_b0, A, 128, 64);
  // conv1: MFMA stride-2 implicit GEMM, LDS-staged weights, A -> B
  conv4s2_mfma<64, 128, true><<<dim3(64, 1, N), blk, 0, stream>>>(
      A, wpk1, enc_b1, B);

  // --- prepacks into A's tail (A dead: conv1 consumed it) ---
  prep_w3s<128, 128><<<dim3(72), blk, 0, stream>>>(enc_wf, wpkF);
  prep_w3s<128, 32><<<dim3(18), blk, 0, stream>>>(enc_res_w1, wpkEa);
  prep_w3s<128, 32><<<dim3(18), blk, 0, stream>>>(
      enc_res_w1 + (size_t)32 * 128 * 9, wpkEb);
  prep_w3s<64, 128><<<dim3(36), blk, 0, stream>>>(dec_w, wpkD);
  prep_w3s<128, 32><<<dim3(18), blk, 0, stream>>>(dec_res_w1, wpkDa);
  prep_w3s<128, 32><<<dim3(18), blk, 0, stream>>>(
      dec_res_w1 + (size_t)32 * 128 * 9, wpkDb);
  prep_cb<<<dim3(16), blk, 0, stream>>>(codebook, cbpk);
  cvt_cbn<<<dim3(2), blk, 0, stream>>>(codebook, cbn);
  prep_w1<32, 128><<<dim3(2), blk, 0, stream>>>(enc_res_w2, wpkR2Ea);
  prep_w1<32, 128><<<dim3(2), blk, 0, stream>>>(
      enc_res_w2 + (size_t)128 * 32, wpkR2Eb);
  prep_w1<32, 128><<<dim3(2), blk, 0, stream>>>(dec_res_w2, wpkR2Da);
  prep_w1<32, 128><<<dim3(2), blk, 0, stream>>>(
      dec_res_w2 + (size_t)128 * 32, wpkR2Db);
  prep_w1<128, 64><<<dim3(4), blk, 0, stream>>>(pre_w, wpkP);

  // convf: MFMA, 2 rows/block, COT-tiled 2x64 (input B already relu'd)
  conv3_mfma2<128, 128, 64, false><<<dim3(32, 2, N), blk, 0, stream>>>(
      B, wpkF, enc_bf, C);
  // enc res stack on C
  conv3_mfma2<128, 32, 32, true><<<dim3(32, 1, N), blk, 0, stream>>>(
      C, wpkEa, enc_res_b1, A);
  conv1x1_mfma<32, 128, true, true, false><<<dim3(64, 1, N), blk, 0, stream>>>(
      A, wpkR2Ea, enc_res_b2, C, 4096);
  conv3_mfma2<128, 32, 32, true><<<dim3(32, 1, N), blk, 0, stream>>>(
      C, wpkEb, enc_res_b1 + 32, A);
  conv1x1_mfma<32, 128, true, true, true><<<dim3(64, 1, N), blk, 0, stream>>>(
      A, wpkR2Eb, enc_res_b2 + 128, C, 4096);
  // pre: C already relu'd -> z in A
  conv1x1_mfma<128, 64, false, false, false><<<dim3(64, 1, N), blk, 0, stream>>>(
      C, wpkP, pre_b, A, 4096);

  // --- up0 weight prepack into C (C dead after pre) ---
  prep_wts<128, 64><<<dim3(64), blk, 0, stream>>>(up_w0, wpkT);

  // --- VQ (in-place on A) via MFMA ---
  vq_mfma<<<dim3(1024), blk, 0, stream>>>(codebook, cbpk, cbn, A);

  // --- Decoder ---
  conv3_mfma2<64, 128, 64, false><<<dim3(32, 2, N), blk, 0, stream>>>(
      A, wpkD, dec_b, B);
  conv3_mfma2<128, 32, 32, true><<<dim3(32, 1, N), blk, 0, stream>>>(
      B, wpkDa, dec_res_b1, A);
  conv1x1_mfma<32, 128, true, true, false><<<dim3(64, 1, N), blk, 0, stream>>>(
      A, wpkR2Da, dec_res_b2, B, 4096);
  conv3_mfma2<128, 32, 32, true><<<dim3(32, 1, N), blk, 0, stream>>>(
      B, wpkDb, dec_res_b1 + 32, A);
  conv1x1_mfma<32, 128, true, true, true><<<dim3(64, 1, N), blk, 0, stream>>>(
      A, wpkR2Db, dec_res_b2 + 128, B, 4096);
  // up0: MFMA ConvTranspose, LDS-staged weights, B (relu'd) -> A, ReLU out
  convt_mfma<128, 64, true><<<dim3(64, 1, N), blk, 0, stream>>>(
      B, wpkT, up_b0, A);
  // up1: A -> out(16,3,256,256)
  convt_row<64, 3, false, false, 128><<<dim3(128, 1, N), blk, 0, stream>>>(
      A, up_w1, up_b1, out, 128, 3);
}